// Round 6
// baseline (424.602 us; speedup 1.0000x reference)
//
#include <hip/hip_runtime.h>
#include <math.h>

#define EMB 2048
#define NH 16
#define HD 128
#define BATCH 8
#define SEQ 16
#define KVLEN 4096
#define KSPLIT 11
#define MROWS (BATCH * SEQ) /* 128 */

__device__ __forceinline__ float dot4(float4 a, float4 b) {
  return a.x * b.x + a.y * b.y + a.z * b.z + a.w * b.w;
}
__device__ __forceinline__ float blo(unsigned int w) {
  return __uint_as_float(w << 16);
}
__device__ __forceinline__ float bhi(unsigned int w) {
  return __uint_as_float(w & 0xffff0000u);
}
// pack two floats to bf16x2 (RNE)
__device__ __forceinline__ unsigned int pk2(float x, float y) {
  unsigned int ux = __float_as_uint(x);
  unsigned int uy = __float_as_uint(y);
  ux = (ux + 0x7fffu + ((ux >> 16) & 1u)) >> 16;
  uy = (uy + 0x7fffu + ((uy >> 16) & 1u)) & 0xffff0000u;
  return ux | uy;
}

// ---------------------------------------------------------------------------
// fp32 GEMM: Ypart[r][d] = sum_{c in k-slice} X[r][c] * W[d][c].
// (unchanged from R3/R4 — working)
// ---------------------------------------------------------------------------
__global__ __launch_bounds__(256) void gemm_f32(
    const float* __restrict__ X, const float* __restrict__ W0,
    const float* __restrict__ W1, const float* __restrict__ W2,
    float* __restrict__ Yp) {
  const int z = blockIdx.z;
  const float* __restrict__ W = (z == 0) ? W0 : (z == 1) ? W1 : W2;
  const int kp = blockIdx.y;       // 0..7
  const int c0 = blockIdx.x * 64;  // col block
  const int k0 = kp * 256;         // k-slice start
  const int tid = threadIdx.x;
  const int lane = tid & 63;
  const int wid = tid >> 6;

  const int colg = lane & 15;
  const int rbase = wid * 32 + (lane >> 4) * 8;
  const int perm = lane & 7;

  __shared__ float wt[2][64 * 32];

  float acc[8][4];
#pragma unroll
  for (int i = 0; i < 8; ++i)
#pragma unroll
    for (int c = 0; c < 4; ++c) acc[i][c] = 0.f;

  const int sc0 = tid >> 3, sk = tid & 7;
  const int sc1 = 32 + sc0;
  const float* wsrc0 = &W[(size_t)(c0 + sc0) * EMB + k0 + sk * 4];
  const float* wsrc1 = &W[(size_t)(c0 + sc1) * EMB + k0 + sk * 4];
  const int wo0 = sc0 * 32 + 4 * (sk ^ ((sc0 >> 2) & 7));
  const int wo1 = sc1 * 32 + 4 * (sk ^ ((sc1 >> 2) & 7));

  const float* xbase = X + (size_t)rbase * EMB + k0;

  float4 s0 = *(const float4*)(wsrc0);
  float4 s1 = *(const float4*)(wsrc1);
  *(float4*)&wt[0][wo0] = s0;
  *(float4*)&wt[0][wo1] = s1;
  float4 n0 = *(const float4*)(wsrc0 + 32);
  float4 n1 = *(const float4*)(wsrc1 + 32);
  __syncthreads();

  for (int t = 0; t < 8; ++t) {
    const int buf = t & 1;
    const float* wb = &wt[buf][0];
    const int xoff = t * 32;
#pragma unroll
    for (int k4 = 0; k4 < 8; ++k4) {
      float4 xv[8];
#pragma unroll
      for (int i = 0; i < 8; ++i)
        xv[i] = *(const float4*)&xbase[(size_t)i * EMB + xoff + k4 * 4];
      float4 wv[4];
#pragma unroll
      for (int c = 0; c < 4; ++c)
        wv[c] = *(const float4*)&wb[(4 * colg + c) * 32 + 4 * (k4 ^ perm)];
#pragma unroll
      for (int i = 0; i < 8; ++i)
#pragma unroll
        for (int c = 0; c < 4; ++c)
          acc[i][c] = fmaf(xv[i].w, wv[c].w,
                      fmaf(xv[i].z, wv[c].z,
                      fmaf(xv[i].y, wv[c].y,
                      fmaf(xv[i].x, wv[c].x, acc[i][c]))));
    }
    if (t < 7) {
      *(float4*)&wt[buf ^ 1][wo0] = n0;
      *(float4*)&wt[buf ^ 1][wo1] = n1;
      if (t < 6) {
        n0 = *(const float4*)(wsrc0 + (t + 2) * 32);
        n1 = *(const float4*)(wsrc1 + (t + 2) * 32);
      }
    }
    __syncthreads();
  }

  float* yout = Yp + ((size_t)(z * 8 + kp) * MROWS + rbase) * EMB + c0 + colg * 4;
#pragma unroll
  for (int i = 0; i < 8; ++i)
    *(float4*)&yout[(size_t)i * EMB] =
        make_float4(acc[i][0], acc[i][1], acc[i][2], acc[i][3]);
}

// ---------------------------------------------------------------------------
// Sum 8 split-K parts per matrix; apply RoPE to q,k (z=0,1); v plain.
// ---------------------------------------------------------------------------
__global__ __launch_bounds__(256) void sum_qkv_rope_k(
    const float* __restrict__ parts, float* __restrict__ yq,
    float* __restrict__ yk, float* __restrict__ yv) {
  const int idx4 = blockIdx.x * 256 + threadIdx.x;
  const int idx = idx4 << 2;
  const int row = idx >> 11;
  const int col = idx & 2047;
  const float s = (float)(row & 15);
  const int hd = col & 127;
  const float a0 = s * powf(10000.0f, -(float)hd * (1.0f / 128.0f));
  const float a1 = s * powf(10000.0f, -(float)(hd + 2) * (1.0f / 128.0f));
  float sn0, cs0, sn1, cs1;
  sincosf(a0, &sn0, &cs0);
  sincosf(a1, &sn1, &cs1);
  const float4* p = (const float4*)parts;
  float* outs[3] = {yq, yk, yv};
#pragma unroll
  for (int z = 0; z < 3; ++z) {
    float4 v = make_float4(0.f, 0.f, 0.f, 0.f);
#pragma unroll
    for (int k = 0; k < 8; ++k) {
      float4 a = p[((size_t)(z * 8 + k)) * 65536 + idx4];
      v.x += a.x; v.y += a.y; v.z += a.z; v.w += a.w;
    }
    if (z < 2) {
      float4 r;
      r.x = v.x * cs0 - v.y * sn0;
      r.y = v.x * sn0 + v.y * cs0;
      r.z = v.z * cs1 - v.w * sn1;
      r.w = v.z * sn1 + v.w * cs1;
      v = r;
    }
    ((float4*)outs[z])[idx4] = v;
  }
}

// ---------------------------------------------------------------------------
// sum 8 split-K parts + bias -> final output
// ---------------------------------------------------------------------------
__global__ __launch_bounds__(256) void sum8_bias_k(const float* __restrict__ parts,
                                                   const float* __restrict__ bo,
                                                   float* __restrict__ out) {
  const size_t idx = (size_t)blockIdx.x * 256 + threadIdx.x;
  float4 s = *(const float4*)&bo[(idx << 2) & 2047];
  const float4* p = (const float4*)parts;
#pragma unroll
  for (int k = 0; k < 8; ++k) {
    float4 v = p[(size_t)k * 65536 + idx];
    s.x += v.x; s.y += v.y; s.z += v.z; s.w += v.w;
  }
  ((float4*)out)[idx] = s;
}

// ---------------------------------------------------------------------------
// Flash-decoding attention partial — bf16-LDS, double-buffered, swizzled.
// Grid (KSPLIT=11, NH, BATCH), 256 threads. Wave = 4 q-rows.
// Lane = (kslot 0..7: keys kslot+8i, g 0..7: d-slice 16g..+15).
// K/V tiles staged as packed bf16x2 (RNE) into LDS; rotate swizzle
// slot=(chunk+row)&15 makes aligned-8-lane groups hit 8 distinct bank quads
// on both write and read. Dbuf: global loads for t+1 issued into regs before
// compute of t, written to LDS after the first barrier. 3 tiles per block.
// ---------------------------------------------------------------------------
__global__ __launch_bounds__(256, 2) void attn_partial_k(
    const float* __restrict__ q, const float* __restrict__ knew,
    const float* __restrict__ vnew, const float* __restrict__ ck,
    const float* __restrict__ cv, const int* __restrict__ sp_ptr,
    float* __restrict__ po, float* __restrict__ pm, float* __restrict__ pl) {
  const int j = blockIdx.x, h = blockIdx.y, b = blockIdx.z;
  const int tid = threadIdx.x;
  const int wid = tid >> 6;
  const int lane = tid & 63;
  const int kslot = lane & 7;
  const int g = lane >> 3;
  const int sp = *sp_ptr;
  const int L = sp + SEQ;
  const int nTiles = (L + 63) >> 6;
  const int tA = (nTiles * j) / KSPLIT;
  const int tB = (nTiles * (j + 1)) / KSPLIT;

  __shared__ unsigned int kt[2][64][64];  // 32 KB (bf16x2)
  __shared__ unsigned int vt[2][64][64];  // 32 KB

  const float qscale = 0.08838834764831845f;  // 1/sqrt(128)
  float4 Q[4][4];
  {
    const float* qb = q + (size_t)(b * SEQ + (wid << 2)) * EMB + h * HD + (g << 4);
#pragma unroll
    for (int qq = 0; qq < 4; ++qq)
#pragma unroll
      for (int c = 0; c < 4; ++c) {
        float4 v = *(const float4*)&qb[(size_t)qq * EMB + (c << 2)];
        v.x *= qscale; v.y *= qscale; v.z *= qscale; v.w *= qscale;
        Q[qq][c] = v;
      }
  }

  float acc[4][16];
#pragma unroll
  for (int qq = 0; qq < 4; ++qq)
#pragma unroll
    for (int d = 0; d < 16; ++d) acc[qq][d] = 0.f;
  float m[4] = {-1e30f, -1e30f, -1e30f, -1e30f};
  float l[4] = {0.f, 0.f, 0.f, 0.f};

  // staging roles: thread covers dst chunks (r = 16k+rr, c = cc), k=0..3
  const int rr = tid >> 4;        // 0..15
  const int cc = tid & 15;        // 0..15 (chunk of 8 d-values)
  const int ss = (cc + rr) & 15;  // rotate slot (16k drops mod 16)
  const size_t ckRow = (size_t)b * KVLEN * EMB + h * HD + cc * 8;
  const size_t knRow = (size_t)b * SEQ * EMB + h * HD + cc * 8;

  float4 ka[4], kb[4], va[4], vb[4];  // prefetch regs

  // ---- prologue: load + write tile tA into buf 0 ----
  {
    const int t0 = tA << 6;
    for (int k = 0; k < 4; ++k) {
      const int gkE = min(t0 + (k << 4) + rr, L - 1);
      const float* ksp;
      const float* vsp;
      if (gkE < sp) {
        ksp = ck + ckRow + (size_t)gkE * EMB;
        vsp = cv + ckRow + (size_t)gkE * EMB;
      } else {
        ksp = knew + knRow + (size_t)(gkE - sp) * EMB;
        vsp = vnew + knRow + (size_t)(gkE - sp) * EMB;
      }
      ka[k] = ((const float4*)ksp)[0];
      kb[k] = ((const float4*)ksp)[1];
      va[k] = ((const float4*)vsp)[0];
      vb[k] = ((const float4*)vsp)[1];
    }
    for (int k = 0; k < 4; ++k) {
      const int r = (k << 4) + rr;
      *(uint4*)&kt[0][r][ss << 2] =
          make_uint4(pk2(ka[k].x, ka[k].y), pk2(ka[k].z, ka[k].w),
                     pk2(kb[k].x, kb[k].y), pk2(kb[k].z, kb[k].w));
      *(uint4*)&vt[0][r][ss << 2] =
          make_uint4(pk2(va[k].x, va[k].y), pk2(va[k].z, va[k].w),
                     pk2(vb[k].x, vb[k].y), pk2(vb[k].z, vb[k].w));
    }
  }
  __syncthreads();

  for (int t = tA; t < tB; ++t) {
    const int cur = (t - tA) & 1;
    const bool hn = (t + 1 < tB);
    if (hn) {
      const int t0n = (t + 1) << 6;
      for (int k = 0; k < 4; ++k) {
        const int gkE = min(t0n + (k << 4) + rr, L - 1);
        const float* ksp;
        const float* vsp;
        if (gkE < sp) {
          ksp = ck + ckRow + (size_t)gkE * EMB;
          vsp = cv + ckRow + (size_t)gkE * EMB;
        } else {
          ksp = knew + knRow + (size_t)(gkE - sp) * EMB;
          vsp = vnew + knRow + (size_t)(gkE - sp) * EMB;
        }
        ka[k] = ((const float4*)ksp)[0];
        kb[k] = ((const float4*)ksp)[1];
        va[k] = ((const float4*)vsp)[0];
        vb[k] = ((const float4*)vsp)[1];
      }
    }
    const int t0 = t << 6;

    // ---- scores: lane's 8 keys x 4 q over its 16-d slice ----
    float p8[4][8];
#pragma unroll
    for (int i = 0; i < 8; ++i) {
      const int r = kslot + (i << 3);
      const int s0 = ((g << 1) + r) & 15;
      const int s1 = (s0 + 1) & 15;
      const uint4 A = *(const uint4*)&kt[cur][r][s0 << 2];
      const uint4 B = *(const uint4*)&kt[cur][r][s1 << 2];
      const float k0 = blo(A.x), k1 = bhi(A.x), k2 = blo(A.y), k3 = bhi(A.y);
      const float k4 = blo(A.z), k5 = bhi(A.z), k6 = blo(A.w), k7 = bhi(A.w);
      const float k8 = blo(B.x), k9 = bhi(B.x), k10 = blo(B.y), k11 = bhi(B.y);
      const float k12 = blo(B.z), k13 = bhi(B.z), k14 = blo(B.w), k15 = bhi(B.w);
#pragma unroll
      for (int qq = 0; qq < 4; ++qq) {
        float s = k0 * Q[qq][0].x;
        s = fmaf(k1, Q[qq][0].y, s);
        s = fmaf(k2, Q[qq][0].z, s);
        s = fmaf(k3, Q[qq][0].w, s);
        s = fmaf(k4, Q[qq][1].x, s);
        s = fmaf(k5, Q[qq][1].y, s);
        s = fmaf(k6, Q[qq][1].z, s);
        s = fmaf(k7, Q[qq][1].w, s);
        s = fmaf(k8, Q[qq][2].x, s);
        s = fmaf(k9, Q[qq][2].y, s);
        s = fmaf(k10, Q[qq][2].z, s);
        s = fmaf(k11, Q[qq][2].w, s);
        s = fmaf(k12, Q[qq][3].x, s);
        s = fmaf(k13, Q[qq][3].y, s);
        s = fmaf(k14, Q[qq][3].z, s);
        s = fmaf(k15, Q[qq][3].w, s);
        p8[qq][i] = s;
      }
    }
    // ---- reduce over g (lane bits 3..5), mask tail ----
#pragma unroll
    for (int qq = 0; qq < 4; ++qq)
#pragma unroll
      for (int i = 0; i < 8; ++i) {
        float v = p8[qq][i];
        v += __shfl_xor(v, 8);
        v += __shfl_xor(v, 16);
        v += __shfl_xor(v, 32);
        if (t0 + kslot + (i << 3) >= L) v = -3.0e38f;
        p8[qq][i] = v;
      }
    // ---- online softmax per q-row (reduce over kslot bits 0..2) ----
#pragma unroll
    for (int qq = 0; qq < 4; ++qq) {
      float tm = p8[qq][0];
#pragma unroll
      for (int i = 1; i < 8; ++i) tm = fmaxf(tm, p8[qq][i]);
      tm = fmaxf(tm, __shfl_xor(tm, 1));
      tm = fmaxf(tm, __shfl_xor(tm, 2));
      tm = fmaxf(tm, __shfl_xor(tm, 4));
      float mn = fmaxf(m[qq], tm);
      float sc = __expf(m[qq] - mn);
      float ls = 0.f;
#pragma unroll
      for (int i = 0; i < 8; ++i) {
        float pe = __expf(p8[qq][i] - mn);
        p8[qq][i] = pe;
        ls += pe;
      }
      ls += __shfl_xor(ls, 1);
      ls += __shfl_xor(ls, 2);
      ls += __shfl_xor(ls, 4);
      l[qq] = l[qq] * sc + ls;
      m[qq] = mn;
#pragma unroll
      for (int d = 0; d < 16; ++d) acc[qq][d] *= sc;
    }
    // ---- PV: lane's 8 keys into its 16-d slice ----
#pragma unroll
    for (int i = 0; i < 8; ++i) {
      const int r = kslot + (i << 3);
      const int s0 = ((g << 1) + r) & 15;
      const int s1 = (s0 + 1) & 15;
      const uint4 A = *(const uint4*)&vt[cur][r][s0 << 2];
      const uint4 B = *(const uint4*)&vt[cur][r][s1 << 2];
      const float v0 = blo(A.x), v1 = bhi(A.x), v2 = blo(A.y), v3 = bhi(A.y);
      const float v4 = blo(A.z), v5 = bhi(A.z), v6 = blo(A.w), v7 = bhi(A.w);
      const float v8 = blo(B.x), v9 = bhi(B.x), v10 = blo(B.y), v11 = bhi(B.y);
      const float v12 = blo(B.z), v13 = bhi(B.z), v14 = blo(B.w), v15 = bhi(B.w);
#pragma unroll
      for (int qq = 0; qq < 4; ++qq) {
        const float pv = p8[qq][i];
        acc[qq][0] = fmaf(pv, v0, acc[qq][0]);
        acc[qq][1] = fmaf(pv, v1, acc[qq][1]);
        acc[qq][2] = fmaf(pv, v2, acc[qq][2]);
        acc[qq][3] = fmaf(pv, v3, acc[qq][3]);
        acc[qq][4] = fmaf(pv, v4, acc[qq][4]);
        acc[qq][5] = fmaf(pv, v5, acc[qq][5]);
        acc[qq][6] = fmaf(pv, v6, acc[qq][6]);
        acc[qq][7] = fmaf(pv, v7, acc[qq][7]);
        acc[qq][8] = fmaf(pv, v8, acc[qq][8]);
        acc[qq][9] = fmaf(pv, v9, acc[qq][9]);
        acc[qq][10] = fmaf(pv, v10, acc[qq][10]);
        acc[qq][11] = fmaf(pv, v11, acc[qq][11]);
        acc[qq][12] = fmaf(pv, v12, acc[qq][12]);
        acc[qq][13] = fmaf(pv, v13, acc[qq][13]);
        acc[qq][14] = fmaf(pv, v14, acc[qq][14]);
        acc[qq][15] = fmaf(pv, v15, acc[qq][15]);
      }
    }
    __syncthreads();  // S1: all reads of buf `cur` done
    if (hn) {
      for (int k = 0; k < 4; ++k) {
        const int r = (k << 4) + rr;
        *(uint4*)&kt[cur ^ 1][r][ss << 2] =
            make_uint4(pk2(ka[k].x, ka[k].y), pk2(ka[k].z, ka[k].w),
                       pk2(kb[k].x, kb[k].y), pk2(kb[k].z, kb[k].w));
        *(uint4*)&vt[cur ^ 1][r][ss << 2] =
            make_uint4(pk2(va[k].x, va[k].y), pk2(va[k].z, va[k].w),
                       pk2(vb[k].x, vb[k].y), pk2(vb[k].z, vb[k].w));
      }
    }
    __syncthreads();  // S2: next tile staged
  }

  // ---- reduce acc over kslot lanes; write partials ----
#pragma unroll
  for (int qq = 0; qq < 4; ++qq)
#pragma unroll
    for (int d = 0; d < 16; ++d) {
      float v = acc[qq][d];
      v += __shfl_xor(v, 1);
      v += __shfl_xor(v, 2);
      v += __shfl_xor(v, 4);
      acc[qq][d] = v;
    }
  const size_t pair = (size_t)(b * NH + h);
  const size_t pb = (pair * KSPLIT + j) * SEQ + (wid << 2);
  if (kslot == 0) {
#pragma unroll
    for (int qq = 0; qq < 4; ++qq)
#pragma unroll
      for (int c = 0; c < 4; ++c)
        *(float4*)&po[(pb + qq) * HD + (g << 4) + (c << 2)] =
            make_float4(acc[qq][(c << 2)], acc[qq][(c << 2) + 1],
                        acc[qq][(c << 2) + 2], acc[qq][(c << 2) + 3]);
  }
  if (lane == 0) {
#pragma unroll
    for (int qq = 0; qq < 4; ++qq) {
      pm[pb + qq] = m[qq];
      pl[pb + qq] = l[qq];
    }
  }
}

// ---------------------------------------------------------------------------
// Combine KSPLIT partials -> attention output (B,S,H*D) row-major.
// ---------------------------------------------------------------------------
__global__ __launch_bounds__(256) void combine_k(const float* __restrict__ po,
                                                 const float* __restrict__ pm,
                                                 const float* __restrict__ pl,
                                                 float* __restrict__ attn) {
  const int pair = blockIdx.x;
  const int b = pair >> 4, h = pair & 15;
  const int tid = threadIdx.x;
  const int d = tid & 127, gq = tid >> 7;
#pragma unroll
  for (int qi = 0; qi < 8; ++qi) {
    int qq = gq * 8 + qi;
    float mj[KSPLIT], lj[KSPLIT];
    float Mx = -1e30f;
#pragma unroll
    for (int jj = 0; jj < KSPLIT; ++jj) {
      mj[jj] = pm[((size_t)pair * KSPLIT + jj) * SEQ + qq];
      lj[jj] = pl[((size_t)pair * KSPLIT + jj) * SEQ + qq];
      Mx = fmaxf(Mx, mj[jj]);
    }
    float Ls = 0.f, o = 0.f;
#pragma unroll
    for (int jj = 0; jj < KSPLIT; ++jj) {
      float w = __expf(mj[jj] - Mx);
      Ls += lj[jj] * w;
      o += po[(((size_t)pair * KSPLIT + jj) * SEQ + qq) * HD + d] * w;
    }
    attn[(size_t)(b * SEQ + qq) * EMB + h * HD + d] = o / Ls;
  }
}

// ---------------------------------------------------------------------------
extern "C" void kernel_launch(void* const* d_in, const int* in_sizes, int n_in,
                              void* d_out, int out_size, void* d_ws,
                              size_t ws_size, hipStream_t stream) {
  const float* x = (const float*)d_in[0];
  const float* Wq = (const float*)d_in[1];
  const float* Wk = (const float*)d_in[2];
  const float* Wv = (const float*)d_in[3];
  const float* Wo = (const float*)d_in[4];
  const float* bo = (const float*)d_in[5];
  const float* ck = (const float*)d_in[6];
  const float* cv = (const float*)d_in[7];
  const int* sp = (const int*)d_in[8];
  float* out = (float*)d_out;

  float* ws = (float*)d_ws;
  const size_t U = 262144;  // 128*2048 floats
  float* yq = ws;
  float* yk = ws + U * 1;
  float* yv = ws + U * 2;
  float* attn = ws + U * 3;
  float* qkvParts = ws + U * 4;       // [4,28) — dead after sum_qkv_rope_k
  float* po = ws + U * 4;             // reuses qkvParts: 11U -> [4,15)
  float* pm = ws + U * 15;            // 22528 floats
  float* pl = ws + U * 15 + 32768;    // 22528 floats
  float* woParts = ws + U * 16;       // 8U -> [16,24) — after po dead

  // 1) QKV projection, split-K=8
  gemm_f32<<<dim3(32, 8, 3), 256, 0, stream>>>(x, Wq, Wk, Wv, qkvParts);

  // 2) sum parts + RoPE on q,k
  sum_qkv_rope_k<<<dim3(256), 256, 0, stream>>>(qkvParts, yq, yk, yv);

  // 3) flash-decoding attention partials (bf16-LDS, dbuf, 3 tiles/block)
  attn_partial_k<<<dim3(KSPLIT, NH, BATCH), 256, 0, stream>>>(
      yq, yk, yv, ck, cv, sp, po, pm, pl);

  // 4) combine -> attn (row-major)
  combine_k<<<dim3(BATCH * NH), 256, 0, stream>>>(po, pm, pl, attn);

  // 5) output projection, split-K=8
  gemm_f32<<<dim3(32, 8, 1), 256, 0, stream>>>(attn, Wo, Wo, Wo, woParts);

  // 6) sum parts + bias -> out
  sum8_bias_k<<<dim3(256), 256, 0, stream>>>(woParts, bo, out);

  (void)in_sizes; (void)n_in; (void)out_size; (void)ws_size;
}

// Round 8
// 379.668 us; speedup vs baseline: 1.1184x; 1.1184x over previous
//
#include <hip/hip_runtime.h>
#include <math.h>

#define EMB 2048
#define NH 16
#define HD 128
#define BATCH 8
#define SEQ 16
#define KVLEN 4096
#define KSPLIT 11
#define MROWS (BATCH * SEQ) /* 128 */

__device__ __forceinline__ float dot4(float4 a, float4 b) {
  return a.x * b.x + a.y * b.y + a.z * b.z + a.w * b.w;
}
__device__ __forceinline__ float blo(unsigned int w) {
  return __uint_as_float(w << 16);
}
__device__ __forceinline__ float bhi(unsigned int w) {
  return __uint_as_float(w & 0xffff0000u);
}
// pack two floats to bf16x2 (RNE)
__device__ __forceinline__ unsigned int pk2(float x, float y) {
  unsigned int ux = __float_as_uint(x);
  unsigned int uy = __float_as_uint(y);
  ux = (ux + 0x7fffu + ((ux >> 16) & 1u)) >> 16;
  uy = (uy + 0x7fffu + ((uy >> 16) & 1u)) & 0xffff0000u;
  return ux | uy;
}

// ---------------------------------------------------------------------------
// fp32 GEMM: Ypart[r][d] = sum_{c in k-slice} X[r][c] * W[d][c].
// (unchanged from R3/R4 — working)
// ---------------------------------------------------------------------------
__global__ __launch_bounds__(256) void gemm_f32(
    const float* __restrict__ X, const float* __restrict__ W0,
    const float* __restrict__ W1, const float* __restrict__ W2,
    float* __restrict__ Yp) {
  const int z = blockIdx.z;
  const float* __restrict__ W = (z == 0) ? W0 : (z == 1) ? W1 : W2;
  const int kp = blockIdx.y;       // 0..7
  const int c0 = blockIdx.x * 64;  // col block
  const int k0 = kp * 256;         // k-slice start
  const int tid = threadIdx.x;
  const int lane = tid & 63;
  const int wid = tid >> 6;

  const int colg = lane & 15;
  const int rbase = wid * 32 + (lane >> 4) * 8;
  const int perm = lane & 7;

  __shared__ float wt[2][64 * 32];

  float acc[8][4];
#pragma unroll
  for (int i = 0; i < 8; ++i)
#pragma unroll
    for (int c = 0; c < 4; ++c) acc[i][c] = 0.f;

  const int sc0 = tid >> 3, sk = tid & 7;
  const int sc1 = 32 + sc0;
  const float* wsrc0 = &W[(size_t)(c0 + sc0) * EMB + k0 + sk * 4];
  const float* wsrc1 = &W[(size_t)(c0 + sc1) * EMB + k0 + sk * 4];
  const int wo0 = sc0 * 32 + 4 * (sk ^ ((sc0 >> 2) & 7));
  const int wo1 = sc1 * 32 + 4 * (sk ^ ((sc1 >> 2) & 7));

  const float* xbase = X + (size_t)rbase * EMB + k0;

  float4 s0 = *(const float4*)(wsrc0);
  float4 s1 = *(const float4*)(wsrc1);
  *(float4*)&wt[0][wo0] = s0;
  *(float4*)&wt[0][wo1] = s1;
  float4 n0 = *(const float4*)(wsrc0 + 32);
  float4 n1 = *(const float4*)(wsrc1 + 32);
  __syncthreads();

  for (int t = 0; t < 8; ++t) {
    const int buf = t & 1;
    const float* wb = &wt[buf][0];
    const int xoff = t * 32;
#pragma unroll
    for (int k4 = 0; k4 < 8; ++k4) {
      float4 xv[8];
#pragma unroll
      for (int i = 0; i < 8; ++i)
        xv[i] = *(const float4*)&xbase[(size_t)i * EMB + xoff + k4 * 4];
      float4 wv[4];
#pragma unroll
      for (int c = 0; c < 4; ++c)
        wv[c] = *(const float4*)&wb[(4 * colg + c) * 32 + 4 * (k4 ^ perm)];
#pragma unroll
      for (int i = 0; i < 8; ++i)
#pragma unroll
        for (int c = 0; c < 4; ++c)
          acc[i][c] = fmaf(xv[i].w, wv[c].w,
                      fmaf(xv[i].z, wv[c].z,
                      fmaf(xv[i].y, wv[c].y,
                      fmaf(xv[i].x, wv[c].x, acc[i][c]))));
    }
    if (t < 7) {
      *(float4*)&wt[buf ^ 1][wo0] = n0;
      *(float4*)&wt[buf ^ 1][wo1] = n1;
      if (t < 6) {
        n0 = *(const float4*)(wsrc0 + (t + 2) * 32);
        n1 = *(const float4*)(wsrc1 + (t + 2) * 32);
      }
    }
    __syncthreads();
  }

  float* yout = Yp + ((size_t)(z * 8 + kp) * MROWS + rbase) * EMB + c0 + colg * 4;
#pragma unroll
  for (int i = 0; i < 8; ++i)
    *(float4*)&yout[(size_t)i * EMB] =
        make_float4(acc[i][0], acc[i][1], acc[i][2], acc[i][3]);
}

// ---------------------------------------------------------------------------
// Sum 8 split-K parts per matrix; apply RoPE to q,k (z=0,1); v plain.
// ---------------------------------------------------------------------------
__global__ __launch_bounds__(256) void sum_qkv_rope_k(
    const float* __restrict__ parts, float* __restrict__ yq,
    float* __restrict__ yk, float* __restrict__ yv) {
  const int idx4 = blockIdx.x * 256 + threadIdx.x;
  const int idx = idx4 << 2;
  const int row = idx >> 11;
  const int col = idx & 2047;
  const float s = (float)(row & 15);
  const int hd = col & 127;
  const float a0 = s * powf(10000.0f, -(float)hd * (1.0f / 128.0f));
  const float a1 = s * powf(10000.0f, -(float)(hd + 2) * (1.0f / 128.0f));
  float sn0, cs0, sn1, cs1;
  sincosf(a0, &sn0, &cs0);
  sincosf(a1, &sn1, &cs1);
  const float4* p = (const float4*)parts;
  float* outs[3] = {yq, yk, yv};
#pragma unroll
  for (int z = 0; z < 3; ++z) {
    float4 v = make_float4(0.f, 0.f, 0.f, 0.f);
#pragma unroll
    for (int k = 0; k < 8; ++k) {
      float4 a = p[((size_t)(z * 8 + k)) * 65536 + idx4];
      v.x += a.x; v.y += a.y; v.z += a.z; v.w += a.w;
    }
    if (z < 2) {
      float4 r;
      r.x = v.x * cs0 - v.y * sn0;
      r.y = v.x * sn0 + v.y * cs0;
      r.z = v.z * cs1 - v.w * sn1;
      r.w = v.z * sn1 + v.w * cs1;
      v = r;
    }
    ((float4*)outs[z])[idx4] = v;
  }
}

// ---------------------------------------------------------------------------
// sum 8 split-K parts + bias -> final output
// ---------------------------------------------------------------------------
__global__ __launch_bounds__(256) void sum8_bias_k(const float* __restrict__ parts,
                                                   const float* __restrict__ bo,
                                                   float* __restrict__ out) {
  const size_t idx = (size_t)blockIdx.x * 256 + threadIdx.x;
  float4 s = *(const float4*)&bo[(idx << 2) & 2047];
  const float4* p = (const float4*)parts;
#pragma unroll
  for (int k = 0; k < 8; ++k) {
    float4 v = p[(size_t)k * 65536 + idx];
    s.x += v.x; s.y += v.y; s.z += v.z; s.w += v.w;
  }
  ((float4*)out)[idx] = s;
}

// ---------------------------------------------------------------------------
// Flash-decoding attention partial — bf16-LDS, dbuf, K/V-split staging.
// Grid (KSPLIT=11, NH, BATCH), 256 threads. Wave = 4 q-rows.
// Lane = (kslot 0..7: keys kslot+8i, g 0..7: d-slice 16g..+15).
// amdgpu_waves_per_eu(2,2): pins 2 waves/EU so the allocator uses the full
// 256-VGPR budget (R4/R6 spilled at a 128 allocation). Staging split into
// K-phase and V-phase so prefetch regs peak at 32 not 64:
//   issue K(t+1) -> scores(t) -> B1 -> write K -> issue V(t+1) -> PV(t)
//   -> B2 -> write V -> B3.
// ---------------------------------------------------------------------------
__global__ __launch_bounds__(256)
__attribute__((amdgpu_waves_per_eu(2, 2)))
void attn_partial_k(
    const float* __restrict__ q, const float* __restrict__ knew,
    const float* __restrict__ vnew, const float* __restrict__ ck,
    const float* __restrict__ cv, const int* __restrict__ sp_ptr,
    float* __restrict__ po, float* __restrict__ pm, float* __restrict__ pl) {
  const int j = blockIdx.x, h = blockIdx.y, b = blockIdx.z;
  const int tid = threadIdx.x;
  const int wid = tid >> 6;
  const int lane = tid & 63;
  const int kslot = lane & 7;
  const int g = lane >> 3;
  const int sp = *sp_ptr;
  const int L = sp + SEQ;
  const int nTiles = (L + 63) >> 6;
  const int tA = (nTiles * j) / KSPLIT;
  const int tB = (nTiles * (j + 1)) / KSPLIT;

  __shared__ unsigned int kt[2][64][64];  // 32 KB (bf16x2)
  __shared__ unsigned int vt[2][64][64];  // 32 KB

  const float qscale = 0.08838834764831845f;  // 1/sqrt(128)
  float4 Q[4][4];
  {
    const float* qb = q + (size_t)(b * SEQ + (wid << 2)) * EMB + h * HD + (g << 4);
#pragma unroll
    for (int qq = 0; qq < 4; ++qq)
#pragma unroll
      for (int c = 0; c < 4; ++c) {
        float4 v = *(const float4*)&qb[(size_t)qq * EMB + (c << 2)];
        v.x *= qscale; v.y *= qscale; v.z *= qscale; v.w *= qscale;
        Q[qq][c] = v;
      }
  }

  float acc[4][16];
#pragma unroll
  for (int qq = 0; qq < 4; ++qq)
#pragma unroll
    for (int d = 0; d < 16; ++d) acc[qq][d] = 0.f;
  float m[4] = {-1e30f, -1e30f, -1e30f, -1e30f};
  float l[4] = {0.f, 0.f, 0.f, 0.f};

  // staging roles: thread covers rows r = 16k+rr, chunk cc; slot=(cc+r)&15
  const int rr = tid >> 4;        // 0..15
  const int cc = tid & 15;        // 0..15 (chunk of 8 d-values)
  const int ss = (cc + rr) & 15;  // rotate slot (16k drops mod 16)
  const size_t ckRow = (size_t)b * KVLEN * EMB + h * HD + cc * 8;
  const size_t knRow = (size_t)b * SEQ * EMB + h * HD + cc * 8;

  float4 pfa[4], pfb[4];  // prefetch regs (K-phase then V-phase; disjoint lives)

  // ---- prologue: stage tile tA (K then V, sequential) into buf 0 ----
  {
    const int t0 = tA << 6;
#pragma unroll
    for (int k = 0; k < 4; ++k) {
      const int gkE = min(t0 + (k << 4) + rr, L - 1);
      const float* ksp = (gkE < sp) ? ck + ckRow + (size_t)gkE * EMB
                                    : knew + knRow + (size_t)(gkE - sp) * EMB;
      pfa[k] = ((const float4*)ksp)[0];
      pfb[k] = ((const float4*)ksp)[1];
    }
#pragma unroll
    for (int k = 0; k < 4; ++k)
      *(uint4*)&kt[0][(k << 4) + rr][ss << 2] =
          make_uint4(pk2(pfa[k].x, pfa[k].y), pk2(pfa[k].z, pfa[k].w),
                     pk2(pfb[k].x, pfb[k].y), pk2(pfb[k].z, pfb[k].w));
#pragma unroll
    for (int k = 0; k < 4; ++k) {
      const int gkE = min(t0 + (k << 4) + rr, L - 1);
      const float* vsp = (gkE < sp) ? cv + ckRow + (size_t)gkE * EMB
                                    : vnew + knRow + (size_t)(gkE - sp) * EMB;
      pfa[k] = ((const float4*)vsp)[0];
      pfb[k] = ((const float4*)vsp)[1];
    }
#pragma unroll
    for (int k = 0; k < 4; ++k)
      *(uint4*)&vt[0][(k << 4) + rr][ss << 2] =
          make_uint4(pk2(pfa[k].x, pfa[k].y), pk2(pfa[k].z, pfa[k].w),
                     pk2(pfb[k].x, pfb[k].y), pk2(pfb[k].z, pfb[k].w));
  }
  __syncthreads();

  for (int t = tA; t < tB; ++t) {
    const int cur = (t - tA) & 1;
    const bool hn = (t + 1 < tB);
    const int t0 = t << 6;
    const int t0n = (t + 1) << 6;

    // ---- issue K(t+1) loads (consumed after B1; hidden under scores) ----
    if (hn) {
#pragma unroll
      for (int k = 0; k < 4; ++k) {
        const int gkE = min(t0n + (k << 4) + rr, L - 1);
        const float* ksp = (gkE < sp) ? ck + ckRow + (size_t)gkE * EMB
                                      : knew + knRow + (size_t)(gkE - sp) * EMB;
        pfa[k] = ((const float4*)ksp)[0];
        pfb[k] = ((const float4*)ksp)[1];
      }
    }

    // ---- scores: lane's 8 keys x 4 q over its 16-d slice ----
    float p8[4][8];
#pragma unroll
    for (int i = 0; i < 8; ++i) {
      const int r = kslot + (i << 3);
      const int s0 = ((g << 1) + r) & 15;
      const int s1 = (s0 + 1) & 15;
      const uint4 A = *(const uint4*)&kt[cur][r][s0 << 2];
      const uint4 B = *(const uint4*)&kt[cur][r][s1 << 2];
      const float k0 = blo(A.x), k1 = bhi(A.x), k2 = blo(A.y), k3 = bhi(A.y);
      const float k4 = blo(A.z), k5 = bhi(A.z), k6 = blo(A.w), k7 = bhi(A.w);
      const float k8 = blo(B.x), k9 = bhi(B.x), k10 = blo(B.y), k11 = bhi(B.y);
      const float k12 = blo(B.z), k13 = bhi(B.z), k14 = blo(B.w), k15 = bhi(B.w);
#pragma unroll
      for (int qq = 0; qq < 4; ++qq) {
        float s = k0 * Q[qq][0].x;
        s = fmaf(k1, Q[qq][0].y, s);
        s = fmaf(k2, Q[qq][0].z, s);
        s = fmaf(k3, Q[qq][0].w, s);
        s = fmaf(k4, Q[qq][1].x, s);
        s = fmaf(k5, Q[qq][1].y, s);
        s = fmaf(k6, Q[qq][1].z, s);
        s = fmaf(k7, Q[qq][1].w, s);
        s = fmaf(k8, Q[qq][2].x, s);
        s = fmaf(k9, Q[qq][2].y, s);
        s = fmaf(k10, Q[qq][2].z, s);
        s = fmaf(k11, Q[qq][2].w, s);
        s = fmaf(k12, Q[qq][3].x, s);
        s = fmaf(k13, Q[qq][3].y, s);
        s = fmaf(k14, Q[qq][3].z, s);
        s = fmaf(k15, Q[qq][3].w, s);
        p8[qq][i] = s;
      }
    }
    // ---- reduce over g (lane bits 3..5), mask tail ----
#pragma unroll
    for (int qq = 0; qq < 4; ++qq)
#pragma unroll
      for (int i = 0; i < 8; ++i) {
        float v = p8[qq][i];
        v += __shfl_xor(v, 8);
        v += __shfl_xor(v, 16);
        v += __shfl_xor(v, 32);
        if (t0 + kslot + (i << 3) >= L) v = -3.0e38f;
        p8[qq][i] = v;
      }
    // ---- online softmax per q-row (reduce over kslot bits 0..2) ----
#pragma unroll
    for (int qq = 0; qq < 4; ++qq) {
      float tm = p8[qq][0];
#pragma unroll
      for (int i = 1; i < 8; ++i) tm = fmaxf(tm, p8[qq][i]);
      tm = fmaxf(tm, __shfl_xor(tm, 1));
      tm = fmaxf(tm, __shfl_xor(tm, 2));
      tm = fmaxf(tm, __shfl_xor(tm, 4));
      float mn = fmaxf(m[qq], tm);
      float sc = __expf(m[qq] - mn);
      float ls = 0.f;
#pragma unroll
      for (int i = 0; i < 8; ++i) {
        float pe = __expf(p8[qq][i] - mn);
        p8[qq][i] = pe;
        ls += pe;
      }
      ls += __shfl_xor(ls, 1);
      ls += __shfl_xor(ls, 2);
      ls += __shfl_xor(ls, 4);
      l[qq] = l[qq] * sc + ls;
      m[qq] = mn;
#pragma unroll
      for (int d = 0; d < 16; ++d) acc[qq][d] *= sc;
    }

    __syncthreads();  // B1: all K-reads of buf `cur` done
    if (hn) {
#pragma unroll
      for (int k = 0; k < 4; ++k)
        *(uint4*)&kt[cur ^ 1][(k << 4) + rr][ss << 2] =
            make_uint4(pk2(pfa[k].x, pfa[k].y), pk2(pfa[k].z, pfa[k].w),
                       pk2(pfb[k].x, pfb[k].y), pk2(pfb[k].z, pfb[k].w));
      // ---- issue V(t+1) loads (consumed after B2; hidden under PV) ----
#pragma unroll
      for (int k = 0; k < 4; ++k) {
        const int gkE = min(t0n + (k << 4) + rr, L - 1);
        const float* vsp = (gkE < sp) ? cv + ckRow + (size_t)gkE * EMB
                                      : vnew + knRow + (size_t)(gkE - sp) * EMB;
        pfa[k] = ((const float4*)vsp)[0];
        pfb[k] = ((const float4*)vsp)[1];
      }
    }

    // ---- PV: lane's 8 keys into its 16-d slice ----
#pragma unroll
    for (int i = 0; i < 8; ++i) {
      const int r = kslot + (i << 3);
      const int s0 = ((g << 1) + r) & 15;
      const int s1 = (s0 + 1) & 15;
      const uint4 A = *(const uint4*)&vt[cur][r][s0 << 2];
      const uint4 B = *(const uint4*)&vt[cur][r][s1 << 2];
      const float v0 = blo(A.x), v1 = bhi(A.x), v2 = blo(A.y), v3 = bhi(A.y);
      const float v4 = blo(A.z), v5 = bhi(A.z), v6 = blo(A.w), v7 = bhi(A.w);
      const float v8 = blo(B.x), v9 = bhi(B.x), v10 = blo(B.y), v11 = bhi(B.y);
      const float v12 = blo(B.z), v13 = bhi(B.z), v14 = blo(B.w), v15 = bhi(B.w);
#pragma unroll
      for (int qq = 0; qq < 4; ++qq) {
        const float pv = p8[qq][i];
        acc[qq][0] = fmaf(pv, v0, acc[qq][0]);
        acc[qq][1] = fmaf(pv, v1, acc[qq][1]);
        acc[qq][2] = fmaf(pv, v2, acc[qq][2]);
        acc[qq][3] = fmaf(pv, v3, acc[qq][3]);
        acc[qq][4] = fmaf(pv, v4, acc[qq][4]);
        acc[qq][5] = fmaf(pv, v5, acc[qq][5]);
        acc[qq][6] = fmaf(pv, v6, acc[qq][6]);
        acc[qq][7] = fmaf(pv, v7, acc[qq][7]);
        acc[qq][8] = fmaf(pv, v8, acc[qq][8]);
        acc[qq][9] = fmaf(pv, v9, acc[qq][9]);
        acc[qq][10] = fmaf(pv, v10, acc[qq][10]);
        acc[qq][11] = fmaf(pv, v11, acc[qq][11]);
        acc[qq][12] = fmaf(pv, v12, acc[qq][12]);
        acc[qq][13] = fmaf(pv, v13, acc[qq][13]);
        acc[qq][14] = fmaf(pv, v14, acc[qq][14]);
        acc[qq][15] = fmaf(pv, v15, acc[qq][15]);
      }
    }

    __syncthreads();  // B2: all V-reads of buf `cur` done
    if (hn) {
#pragma unroll
      for (int k = 0; k < 4; ++k)
        *(uint4*)&vt[cur ^ 1][(k << 4) + rr][ss << 2] =
            make_uint4(pk2(pfa[k].x, pfa[k].y), pk2(pfa[k].z, pfa[k].w),
                       pk2(pfb[k].x, pfb[k].y), pk2(pfb[k].z, pfb[k].w));
    }
    __syncthreads();  // B3: next tile fully staged
  }

  // ---- reduce acc over kslot lanes; write partials ----
#pragma unroll
  for (int qq = 0; qq < 4; ++qq)
#pragma unroll
    for (int d = 0; d < 16; ++d) {
      float v = acc[qq][d];
      v += __shfl_xor(v, 1);
      v += __shfl_xor(v, 2);
      v += __shfl_xor(v, 4);
      acc[qq][d] = v;
    }
  const size_t pair = (size_t)(b * NH + h);
  const size_t pb = (pair * KSPLIT + j) * SEQ + (wid << 2);
  if (kslot == 0) {
#pragma unroll
    for (int qq = 0; qq < 4; ++qq)
#pragma unroll
      for (int c = 0; c < 4; ++c)
        *(float4*)&po[(pb + qq) * HD + (g << 4) + (c << 2)] =
            make_float4(acc[qq][(c << 2)], acc[qq][(c << 2) + 1],
                        acc[qq][(c << 2) + 2], acc[qq][(c << 2) + 3]);
  }
  if (lane == 0) {
#pragma unroll
    for (int qq = 0; qq < 4; ++qq) {
      pm[pb + qq] = m[qq];
      pl[pb + qq] = l[qq];
    }
  }
}

// ---------------------------------------------------------------------------
// Combine KSPLIT partials -> attention output (B,S,H*D) row-major.
// ---------------------------------------------------------------------------
__global__ __launch_bounds__(256) void combine_k(const float* __restrict__ po,
                                                 const float* __restrict__ pm,
                                                 const float* __restrict__ pl,
                                                 float* __restrict__ attn) {
  const int pair = blockIdx.x;
  const int b = pair >> 4, h = pair & 15;
  const int tid = threadIdx.x;
  const int d = tid & 127, gq = tid >> 7;
#pragma unroll
  for (int qi = 0; qi < 8; ++qi) {
    int qq = gq * 8 + qi;
    float mj[KSPLIT], lj[KSPLIT];
    float Mx = -1e30f;
#pragma unroll
    for (int jj = 0; jj < KSPLIT; ++jj) {
      mj[jj] = pm[((size_t)pair * KSPLIT + jj) * SEQ + qq];
      lj[jj] = pl[((size_t)pair * KSPLIT + jj) * SEQ + qq];
      Mx = fmaxf(Mx, mj[jj]);
    }
    float Ls = 0.f, o = 0.f;
#pragma unroll
    for (int jj = 0; jj < KSPLIT; ++jj) {
      float w = __expf(mj[jj] - Mx);
      Ls += lj[jj] * w;
      o += po[(((size_t)pair * KSPLIT + jj) * SEQ + qq) * HD + d] * w;
    }
    attn[(size_t)(b * SEQ + qq) * EMB + h * HD + d] = o / Ls;
  }
}

// ---------------------------------------------------------------------------
extern "C" void kernel_launch(void* const* d_in, const int* in_sizes, int n_in,
                              void* d_out, int out_size, void* d_ws,
                              size_t ws_size, hipStream_t stream) {
  const float* x = (const float*)d_in[0];
  const float* Wq = (const float*)d_in[1];
  const float* Wk = (const float*)d_in[2];
  const float* Wv = (const float*)d_in[3];
  const float* Wo = (const float*)d_in[4];
  const float* bo = (const float*)d_in[5];
  const float* ck = (const float*)d_in[6];
  const float* cv = (const float*)d_in[7];
  const int* sp = (const int*)d_in[8];
  float* out = (float*)d_out;

  float* ws = (float*)d_ws;
  const size_t U = 262144;  // 128*2048 floats
  float* yq = ws;
  float* yk = ws + U * 1;
  float* yv = ws + U * 2;
  float* attn = ws + U * 3;
  float* qkvParts = ws + U * 4;       // [4,28) — dead after sum_qkv_rope_k
  float* po = ws + U * 4;             // reuses qkvParts: 11U -> [4,15)
  float* pm = ws + U * 15;            // 22528 floats
  float* pl = ws + U * 15 + 32768;    // 22528 floats
  float* woParts = ws + U * 16;       // 8U -> [16,24) — after po dead

  // 1) QKV projection, split-K=8
  gemm_f32<<<dim3(32, 8, 3), 256, 0, stream>>>(x, Wq, Wk, Wv, qkvParts);

  // 2) sum parts + RoPE on q,k
  sum_qkv_rope_k<<<dim3(256), 256, 0, stream>>>(qkvParts, yq, yk, yv);

  // 3) flash-decoding attention partials (bf16-LDS, dbuf, K/V-split staging)
  attn_partial_k<<<dim3(KSPLIT, NH, BATCH), 256, 0, stream>>>(
      yq, yk, yv, ck, cv, sp, po, pm, pl);

  // 4) combine -> attn (row-major)
  combine_k<<<dim3(BATCH * NH), 256, 0, stream>>>(po, pm, pl, attn);

  // 5) output projection, split-K=8
  gemm_f32<<<dim3(32, 8, 1), 256, 0, stream>>>(attn, Wo, Wo, Wo, woParts);

  // 6) sum parts + bias -> out
  sum8_bias_k<<<dim3(256), 256, 0, stream>>>(woParts, bo, out);

  (void)in_sizes; (void)n_in; (void)out_size; (void)ws_size;
}

// Round 9
// 280.215 us; speedup vs baseline: 1.5153x; 1.3549x over previous
//
#include <hip/hip_runtime.h>
#include <math.h>

#define EMB 2048
#define NH 16
#define HD 128
#define BATCH 8
#define SEQ 16
#define KVLEN 4096
#define KSPLIT 11
#define MROWS (BATCH * SEQ) /* 128 */

__device__ __forceinline__ float blo(unsigned int w) {
  return __uint_as_float(w << 16);
}
__device__ __forceinline__ float bhi(unsigned int w) {
  return __uint_as_float(w & 0xffff0000u);
}
// pack two floats to bf16x2 (RNE)
__device__ __forceinline__ unsigned int pk2(float x, float y) {
  unsigned int ux = __float_as_uint(x);
  unsigned int uy = __float_as_uint(y);
  ux = (ux + 0x7fffu + ((ux >> 16) & 1u)) >> 16;
  uy = (uy + 0x7fffu + ((uy >> 16) & 1u)) & 0xffff0000u;
  return ux | uy;
}

// ---------------------------------------------------------------------------
// fp32 GEMM: Ypart[r][d] = sum_{c in k-slice} X[r][c] * W[d][c].
// (unchanged from R3/R4 — working)
// ---------------------------------------------------------------------------
__global__ __launch_bounds__(256) void gemm_f32(
    const float* __restrict__ X, const float* __restrict__ W0,
    const float* __restrict__ W1, const float* __restrict__ W2,
    float* __restrict__ Yp) {
  const int z = blockIdx.z;
  const float* __restrict__ W = (z == 0) ? W0 : (z == 1) ? W1 : W2;
  const int kp = blockIdx.y;       // 0..7
  const int c0 = blockIdx.x * 64;  // col block
  const int k0 = kp * 256;         // k-slice start
  const int tid = threadIdx.x;
  const int lane = tid & 63;
  const int wid = tid >> 6;

  const int colg = lane & 15;
  const int rbase = wid * 32 + (lane >> 4) * 8;
  const int perm = lane & 7;

  __shared__ float wt[2][64 * 32];

  float acc[8][4];
#pragma unroll
  for (int i = 0; i < 8; ++i)
#pragma unroll
    for (int c = 0; c < 4; ++c) acc[i][c] = 0.f;

  const int sc0 = tid >> 3, sk = tid & 7;
  const int sc1 = 32 + sc0;
  const float* wsrc0 = &W[(size_t)(c0 + sc0) * EMB + k0 + sk * 4];
  const float* wsrc1 = &W[(size_t)(c0 + sc1) * EMB + k0 + sk * 4];
  const int wo0 = sc0 * 32 + 4 * (sk ^ ((sc0 >> 2) & 7));
  const int wo1 = sc1 * 32 + 4 * (sk ^ ((sc1 >> 2) & 7));

  const float* xbase = X + (size_t)rbase * EMB + k0;

  float4 s0 = *(const float4*)(wsrc0);
  float4 s1 = *(const float4*)(wsrc1);
  *(float4*)&wt[0][wo0] = s0;
  *(float4*)&wt[0][wo1] = s1;
  float4 n0 = *(const float4*)(wsrc0 + 32);
  float4 n1 = *(const float4*)(wsrc1 + 32);
  __syncthreads();

  for (int t = 0; t < 8; ++t) {
    const int buf = t & 1;
    const float* wb = &wt[buf][0];
    const int xoff = t * 32;
#pragma unroll
    for (int k4 = 0; k4 < 8; ++k4) {
      float4 xv[8];
#pragma unroll
      for (int i = 0; i < 8; ++i)
        xv[i] = *(const float4*)&xbase[(size_t)i * EMB + xoff + k4 * 4];
      float4 wv[4];
#pragma unroll
      for (int c = 0; c < 4; ++c)
        wv[c] = *(const float4*)&wb[(4 * colg + c) * 32 + 4 * (k4 ^ perm)];
#pragma unroll
      for (int i = 0; i < 8; ++i)
#pragma unroll
        for (int c = 0; c < 4; ++c)
          acc[i][c] = fmaf(xv[i].w, wv[c].w,
                      fmaf(xv[i].z, wv[c].z,
                      fmaf(xv[i].y, wv[c].y,
                      fmaf(xv[i].x, wv[c].x, acc[i][c]))));
    }
    if (t < 7) {
      *(float4*)&wt[buf ^ 1][wo0] = n0;
      *(float4*)&wt[buf ^ 1][wo1] = n1;
      if (t < 6) {
        n0 = *(const float4*)(wsrc0 + (t + 2) * 32);
        n1 = *(const float4*)(wsrc1 + (t + 2) * 32);
      }
    }
    __syncthreads();
  }

  float* yout = Yp + ((size_t)(z * 8 + kp) * MROWS + rbase) * EMB + c0 + colg * 4;
#pragma unroll
  for (int i = 0; i < 8; ++i)
    *(float4*)&yout[(size_t)i * EMB] =
        make_float4(acc[i][0], acc[i][1], acc[i][2], acc[i][3]);
}

// ---------------------------------------------------------------------------
// Sum 8 split-K parts per matrix; apply RoPE to q,k (z=0,1); v plain.
// ---------------------------------------------------------------------------
__global__ __launch_bounds__(256) void sum_qkv_rope_k(
    const float* __restrict__ parts, float* __restrict__ yq,
    float* __restrict__ yk, float* __restrict__ yv) {
  const int idx4 = blockIdx.x * 256 + threadIdx.x;
  const int idx = idx4 << 2;
  const int row = idx >> 11;
  const int col = idx & 2047;
  const float s = (float)(row & 15);
  const int hd = col & 127;
  const float a0 = s * powf(10000.0f, -(float)hd * (1.0f / 128.0f));
  const float a1 = s * powf(10000.0f, -(float)(hd + 2) * (1.0f / 128.0f));
  float sn0, cs0, sn1, cs1;
  sincosf(a0, &sn0, &cs0);
  sincosf(a1, &sn1, &cs1);
  const float4* p = (const float4*)parts;
  float* outs[3] = {yq, yk, yv};
#pragma unroll
  for (int z = 0; z < 3; ++z) {
    float4 v = make_float4(0.f, 0.f, 0.f, 0.f);
#pragma unroll
    for (int k = 0; k < 8; ++k) {
      float4 a = p[((size_t)(z * 8 + k)) * 65536 + idx4];
      v.x += a.x; v.y += a.y; v.z += a.z; v.w += a.w;
    }
    if (z < 2) {
      float4 r;
      r.x = v.x * cs0 - v.y * sn0;
      r.y = v.x * sn0 + v.y * cs0;
      r.z = v.z * cs1 - v.w * sn1;
      r.w = v.z * sn1 + v.w * cs1;
      v = r;
    }
    ((float4*)outs[z])[idx4] = v;
  }
}

// ---------------------------------------------------------------------------
// sum 8 split-K parts + bias -> final output
// ---------------------------------------------------------------------------
__global__ __launch_bounds__(256) void sum8_bias_k(const float* __restrict__ parts,
                                                   const float* __restrict__ bo,
                                                   float* __restrict__ out) {
  const size_t idx = (size_t)blockIdx.x * 256 + threadIdx.x;
  float4 s = *(const float4*)&bo[(idx << 2) & 2047];
  const float4* p = (const float4*)parts;
#pragma unroll
  for (int k = 0; k < 8; ++k) {
    float4 v = p[(size_t)k * 65536 + idx];
    s.x += v.x; s.y += v.y; s.z += v.z; s.w += v.w;
  }
  ((float4*)out)[idx] = s;
}

// ---------------------------------------------------------------------------
// Flash-decoding attention partial — 512 threads, 2 q-rows per wave.
// Grid (KSPLIT=11, NH, BATCH). Wave wid=tid>>6 owns q rows {2wid, 2wid+1}.
// Lane = (kslot 0..7: keys kslot+8i, g 0..7: d-slice 16g..+15).
// Live state per thread: Q 32 + acc 32 + p8 16 + prefetch 16 + decode ~12
// ~= 118 regs -> fits the allocator's 128 tier with NO spill (R4-R8 all
// spilled at 128). bf16 LDS tiles, rotate swizzle, dbuf, K/V-split staging:
//   issue K(t+1) -> scores(t) -> B1 -> write K -> issue V(t+1) -> PV(t)
//   -> B2 -> write V -> B3.
// ---------------------------------------------------------------------------
__global__ __launch_bounds__(512) void attn_partial_k(
    const float* __restrict__ q, const float* __restrict__ knew,
    const float* __restrict__ vnew, const float* __restrict__ ck,
    const float* __restrict__ cv, const int* __restrict__ sp_ptr,
    float* __restrict__ po, float* __restrict__ pm, float* __restrict__ pl) {
  const int j = blockIdx.x, h = blockIdx.y, b = blockIdx.z;
  const int tid = threadIdx.x;
  const int wid = tid >> 6;   // 0..7, q rows 2wid..2wid+1
  const int lane = tid & 63;
  const int kslot = lane & 7;
  const int g = lane >> 3;
  const int sp = *sp_ptr;
  const int L = sp + SEQ;
  const int nTiles = (L + 63) >> 6;
  const int tA = (nTiles * j) / KSPLIT;
  const int tB = (nTiles * (j + 1)) / KSPLIT;

  __shared__ unsigned int kt[2][64][64];  // 16 KB per buf (bf16x2)
  __shared__ unsigned int vt[2][64][64];

  const float qscale = 0.08838834764831845f;  // 1/sqrt(128)
  float4 Q[2][4];
  {
    const float* qb = q + (size_t)(b * SEQ + (wid << 1)) * EMB + h * HD + (g << 4);
#pragma unroll
    for (int qq = 0; qq < 2; ++qq)
#pragma unroll
      for (int c = 0; c < 4; ++c) {
        float4 v = *(const float4*)&qb[(size_t)qq * EMB + (c << 2)];
        v.x *= qscale; v.y *= qscale; v.z *= qscale; v.w *= qscale;
        Q[qq][c] = v;
      }
  }

  float acc[2][16];
#pragma unroll
  for (int qq = 0; qq < 2; ++qq)
#pragma unroll
    for (int d = 0; d < 16; ++d) acc[qq][d] = 0.f;
  float m[2] = {-1e30f, -1e30f};
  float l[2] = {0.f, 0.f};

  // staging roles: thread covers rows {rr, rr+32}, chunk cc; slot=(cc+rr)&15
  const int rr = tid >> 4;        // 0..31
  const int cc = tid & 15;        // chunk of 8 d-values
  const int ss = (cc + rr) & 15;  // rotate slot ((k*32)&15==0)
  const size_t ckRow = (size_t)b * KVLEN * EMB + h * HD + cc * 8;
  const size_t knRow = (size_t)b * SEQ * EMB + h * HD + cc * 8;

  float4 pfa[2], pfb[2];  // prefetch regs (K-phase then V-phase)

  // ---- prologue: stage tile tA (K then V) into buf 0 ----
  {
    const int t0 = tA << 6;
#pragma unroll
    for (int k = 0; k < 2; ++k) {
      const int gkE = min(t0 + (k << 5) + rr, L - 1);
      const float* ksp = (gkE < sp) ? ck + ckRow + (size_t)gkE * EMB
                                    : knew + knRow + (size_t)(gkE - sp) * EMB;
      pfa[k] = ((const float4*)ksp)[0];
      pfb[k] = ((const float4*)ksp)[1];
    }
#pragma unroll
    for (int k = 0; k < 2; ++k)
      *(uint4*)&kt[0][(k << 5) + rr][ss << 2] =
          make_uint4(pk2(pfa[k].x, pfa[k].y), pk2(pfa[k].z, pfa[k].w),
                     pk2(pfb[k].x, pfb[k].y), pk2(pfb[k].z, pfb[k].w));
#pragma unroll
    for (int k = 0; k < 2; ++k) {
      const int gkE = min(t0 + (k << 5) + rr, L - 1);
      const float* vsp = (gkE < sp) ? cv + ckRow + (size_t)gkE * EMB
                                    : vnew + knRow + (size_t)(gkE - sp) * EMB;
      pfa[k] = ((const float4*)vsp)[0];
      pfb[k] = ((const float4*)vsp)[1];
    }
#pragma unroll
    for (int k = 0; k < 2; ++k)
      *(uint4*)&vt[0][(k << 5) + rr][ss << 2] =
          make_uint4(pk2(pfa[k].x, pfa[k].y), pk2(pfa[k].z, pfa[k].w),
                     pk2(pfb[k].x, pfb[k].y), pk2(pfb[k].z, pfb[k].w));
  }
  __syncthreads();

  for (int t = tA; t < tB; ++t) {
    const int cur = (t - tA) & 1;
    const bool hn = (t + 1 < tB);
    const int t0 = t << 6;
    const int t0n = (t + 1) << 6;

    // ---- issue K(t+1) loads (consumed after B1; hidden under scores) ----
    if (hn) {
#pragma unroll
      for (int k = 0; k < 2; ++k) {
        const int gkE = min(t0n + (k << 5) + rr, L - 1);
        const float* ksp = (gkE < sp) ? ck + ckRow + (size_t)gkE * EMB
                                      : knew + knRow + (size_t)(gkE - sp) * EMB;
        pfa[k] = ((const float4*)ksp)[0];
        pfb[k] = ((const float4*)ksp)[1];
      }
    }

    // ---- scores: lane's 8 keys x 2 q, 16-d slice (two 8-d halves) ----
    float p8[2][8];
#pragma unroll
    for (int i = 0; i < 8; ++i) {
      const int r = kslot + (i << 3);
      const int s0 = ((g << 1) + r) & 15;
      const int s1 = (s0 + 1) & 15;
      float sA0, sA1;
      {
        const uint4 A = *(const uint4*)&kt[cur][r][s0 << 2];
        const float k0 = blo(A.x), k1 = bhi(A.x), k2 = blo(A.y), k3 = bhi(A.y);
        const float k4 = blo(A.z), k5 = bhi(A.z), k6 = blo(A.w), k7 = bhi(A.w);
        sA0 = k0 * Q[0][0].x;
        sA0 = fmaf(k1, Q[0][0].y, sA0);
        sA0 = fmaf(k2, Q[0][0].z, sA0);
        sA0 = fmaf(k3, Q[0][0].w, sA0);
        sA0 = fmaf(k4, Q[0][1].x, sA0);
        sA0 = fmaf(k5, Q[0][1].y, sA0);
        sA0 = fmaf(k6, Q[0][1].z, sA0);
        sA0 = fmaf(k7, Q[0][1].w, sA0);
        sA1 = k0 * Q[1][0].x;
        sA1 = fmaf(k1, Q[1][0].y, sA1);
        sA1 = fmaf(k2, Q[1][0].z, sA1);
        sA1 = fmaf(k3, Q[1][0].w, sA1);
        sA1 = fmaf(k4, Q[1][1].x, sA1);
        sA1 = fmaf(k5, Q[1][1].y, sA1);
        sA1 = fmaf(k6, Q[1][1].z, sA1);
        sA1 = fmaf(k7, Q[1][1].w, sA1);
      }
      {
        const uint4 B = *(const uint4*)&kt[cur][r][s1 << 2];
        const float k8 = blo(B.x), k9 = bhi(B.x), k10 = blo(B.y), k11 = bhi(B.y);
        const float k12 = blo(B.z), k13 = bhi(B.z), k14 = blo(B.w), k15 = bhi(B.w);
        sA0 = fmaf(k8, Q[0][2].x, sA0);
        sA0 = fmaf(k9, Q[0][2].y, sA0);
        sA0 = fmaf(k10, Q[0][2].z, sA0);
        sA0 = fmaf(k11, Q[0][2].w, sA0);
        sA0 = fmaf(k12, Q[0][3].x, sA0);
        sA0 = fmaf(k13, Q[0][3].y, sA0);
        sA0 = fmaf(k14, Q[0][3].z, sA0);
        sA0 = fmaf(k15, Q[0][3].w, sA0);
        sA1 = fmaf(k8, Q[1][2].x, sA1);
        sA1 = fmaf(k9, Q[1][2].y, sA1);
        sA1 = fmaf(k10, Q[1][2].z, sA1);
        sA1 = fmaf(k11, Q[1][2].w, sA1);
        sA1 = fmaf(k12, Q[1][3].x, sA1);
        sA1 = fmaf(k13, Q[1][3].y, sA1);
        sA1 = fmaf(k14, Q[1][3].z, sA1);
        sA1 = fmaf(k15, Q[1][3].w, sA1);
      }
      p8[0][i] = sA0;
      p8[1][i] = sA1;
    }
    // ---- reduce over g (lane bits 3..5), mask tail ----
#pragma unroll
    for (int qq = 0; qq < 2; ++qq)
#pragma unroll
      for (int i = 0; i < 8; ++i) {
        float v = p8[qq][i];
        v += __shfl_xor(v, 8);
        v += __shfl_xor(v, 16);
        v += __shfl_xor(v, 32);
        if (t0 + kslot + (i << 3) >= L) v = -3.0e38f;
        p8[qq][i] = v;
      }
    // ---- online softmax per q-row (reduce over kslot bits 0..2) ----
#pragma unroll
    for (int qq = 0; qq < 2; ++qq) {
      float tm = p8[qq][0];
#pragma unroll
      for (int i = 1; i < 8; ++i) tm = fmaxf(tm, p8[qq][i]);
      tm = fmaxf(tm, __shfl_xor(tm, 1));
      tm = fmaxf(tm, __shfl_xor(tm, 2));
      tm = fmaxf(tm, __shfl_xor(tm, 4));
      float mn = fmaxf(m[qq], tm);
      float sc = __expf(m[qq] - mn);
      float ls = 0.f;
#pragma unroll
      for (int i = 0; i < 8; ++i) {
        float pe = __expf(p8[qq][i] - mn);
        p8[qq][i] = pe;
        ls += pe;
      }
      ls += __shfl_xor(ls, 1);
      ls += __shfl_xor(ls, 2);
      ls += __shfl_xor(ls, 4);
      l[qq] = l[qq] * sc + ls;
      m[qq] = mn;
#pragma unroll
      for (int d = 0; d < 16; ++d) acc[qq][d] *= sc;
    }

    __syncthreads();  // B1: all K-reads of buf `cur` done
    if (hn) {
#pragma unroll
      for (int k = 0; k < 2; ++k)
        *(uint4*)&kt[cur ^ 1][(k << 5) + rr][ss << 2] =
            make_uint4(pk2(pfa[k].x, pfa[k].y), pk2(pfa[k].z, pfa[k].w),
                       pk2(pfb[k].x, pfb[k].y), pk2(pfb[k].z, pfb[k].w));
      // ---- issue V(t+1) loads (consumed after B2; hidden under PV) ----
#pragma unroll
      for (int k = 0; k < 2; ++k) {
        const int gkE = min(t0n + (k << 5) + rr, L - 1);
        const float* vsp = (gkE < sp) ? cv + ckRow + (size_t)gkE * EMB
                                      : vnew + knRow + (size_t)(gkE - sp) * EMB;
        pfa[k] = ((const float4*)vsp)[0];
        pfb[k] = ((const float4*)vsp)[1];
      }
    }

    // ---- PV: lane's 8 keys into its 16-d slice (two 8-d halves) ----
#pragma unroll
    for (int i = 0; i < 8; ++i) {
      const int r = kslot + (i << 3);
      const int s0 = ((g << 1) + r) & 15;
      const int s1 = (s0 + 1) & 15;
      const float p0 = p8[0][i], p1 = p8[1][i];
      {
        const uint4 A = *(const uint4*)&vt[cur][r][s0 << 2];
        const float v0 = blo(A.x), v1 = bhi(A.x), v2 = blo(A.y), v3 = bhi(A.y);
        const float v4 = blo(A.z), v5 = bhi(A.z), v6 = blo(A.w), v7 = bhi(A.w);
        acc[0][0] = fmaf(p0, v0, acc[0][0]);
        acc[0][1] = fmaf(p0, v1, acc[0][1]);
        acc[0][2] = fmaf(p0, v2, acc[0][2]);
        acc[0][3] = fmaf(p0, v3, acc[0][3]);
        acc[0][4] = fmaf(p0, v4, acc[0][4]);
        acc[0][5] = fmaf(p0, v5, acc[0][5]);
        acc[0][6] = fmaf(p0, v6, acc[0][6]);
        acc[0][7] = fmaf(p0, v7, acc[0][7]);
        acc[1][0] = fmaf(p1, v0, acc[1][0]);
        acc[1][1] = fmaf(p1, v1, acc[1][1]);
        acc[1][2] = fmaf(p1, v2, acc[1][2]);
        acc[1][3] = fmaf(p1, v3, acc[1][3]);
        acc[1][4] = fmaf(p1, v4, acc[1][4]);
        acc[1][5] = fmaf(p1, v5, acc[1][5]);
        acc[1][6] = fmaf(p1, v6, acc[1][6]);
        acc[1][7] = fmaf(p1, v7, acc[1][7]);
      }
      {
        const uint4 B = *(const uint4*)&vt[cur][r][s1 << 2];
        const float v8 = blo(B.x), v9 = bhi(B.x), v10 = blo(B.y), v11 = bhi(B.y);
        const float v12 = blo(B.z), v13 = bhi(B.z), v14 = blo(B.w), v15 = bhi(B.w);
        acc[0][8] = fmaf(p0, v8, acc[0][8]);
        acc[0][9] = fmaf(p0, v9, acc[0][9]);
        acc[0][10] = fmaf(p0, v10, acc[0][10]);
        acc[0][11] = fmaf(p0, v11, acc[0][11]);
        acc[0][12] = fmaf(p0, v12, acc[0][12]);
        acc[0][13] = fmaf(p0, v13, acc[0][13]);
        acc[0][14] = fmaf(p0, v14, acc[0][14]);
        acc[0][15] = fmaf(p0, v15, acc[0][15]);
        acc[1][8] = fmaf(p1, v8, acc[1][8]);
        acc[1][9] = fmaf(p1, v9, acc[1][9]);
        acc[1][10] = fmaf(p1, v10, acc[1][10]);
        acc[1][11] = fmaf(p1, v11, acc[1][11]);
        acc[1][12] = fmaf(p1, v12, acc[1][12]);
        acc[1][13] = fmaf(p1, v13, acc[1][13]);
        acc[1][14] = fmaf(p1, v14, acc[1][14]);
        acc[1][15] = fmaf(p1, v15, acc[1][15]);
      }
    }

    __syncthreads();  // B2: all V-reads of buf `cur` done
    if (hn) {
#pragma unroll
      for (int k = 0; k < 2; ++k)
        *(uint4*)&vt[cur ^ 1][(k << 5) + rr][ss << 2] =
            make_uint4(pk2(pfa[k].x, pfa[k].y), pk2(pfa[k].z, pfa[k].w),
                       pk2(pfb[k].x, pfb[k].y), pk2(pfb[k].z, pfb[k].w));
    }
    __syncthreads();  // B3: next tile fully staged
  }

  // ---- reduce acc over kslot lanes; write partials ----
#pragma unroll
  for (int qq = 0; qq < 2; ++qq)
#pragma unroll
    for (int d = 0; d < 16; ++d) {
      float v = acc[qq][d];
      v += __shfl_xor(v, 1);
      v += __shfl_xor(v, 2);
      v += __shfl_xor(v, 4);
      acc[qq][d] = v;
    }
  const size_t pair = (size_t)(b * NH + h);
  const size_t pb = (pair * KSPLIT + j) * SEQ + (wid << 1);
  if (kslot == 0) {
#pragma unroll
    for (int qq = 0; qq < 2; ++qq)
#pragma unroll
      for (int c = 0; c < 4; ++c)
        *(float4*)&po[(pb + qq) * HD + (g << 4) + (c << 2)] =
            make_float4(acc[qq][(c << 2)], acc[qq][(c << 2) + 1],
                        acc[qq][(c << 2) + 2], acc[qq][(c << 2) + 3]);
  }
  if (lane == 0) {
#pragma unroll
    for (int qq = 0; qq < 2; ++qq) {
      pm[pb + qq] = m[qq];
      pl[pb + qq] = l[qq];
    }
  }
}

// ---------------------------------------------------------------------------
// Combine KSPLIT partials -> attention output (B,S,H*D) row-major.
// ---------------------------------------------------------------------------
__global__ __launch_bounds__(256) void combine_k(const float* __restrict__ po,
                                                 const float* __restrict__ pm,
                                                 const float* __restrict__ pl,
                                                 float* __restrict__ attn) {
  const int pair = blockIdx.x;
  const int b = pair >> 4, h = pair & 15;
  const int tid = threadIdx.x;
  const int d = tid & 127, gq = tid >> 7;
#pragma unroll
  for (int qi = 0; qi < 8; ++qi) {
    int qq = gq * 8 + qi;
    float mj[KSPLIT], lj[KSPLIT];
    float Mx = -1e30f;
#pragma unroll
    for (int jj = 0; jj < KSPLIT; ++jj) {
      mj[jj] = pm[((size_t)pair * KSPLIT + jj) * SEQ + qq];
      lj[jj] = pl[((size_t)pair * KSPLIT + jj) * SEQ + qq];
      Mx = fmaxf(Mx, mj[jj]);
    }
    float Ls = 0.f, o = 0.f;
#pragma unroll
    for (int jj = 0; jj < KSPLIT; ++jj) {
      float w = __expf(mj[jj] - Mx);
      Ls += lj[jj] * w;
      o += po[(((size_t)pair * KSPLIT + jj) * SEQ + qq) * HD + d] * w;
    }
    attn[(size_t)(b * SEQ + qq) * EMB + h * HD + d] = o / Ls;
  }
}

// ---------------------------------------------------------------------------
extern "C" void kernel_launch(void* const* d_in, const int* in_sizes, int n_in,
                              void* d_out, int out_size, void* d_ws,
                              size_t ws_size, hipStream_t stream) {
  const float* x = (const float*)d_in[0];
  const float* Wq = (const float*)d_in[1];
  const float* Wk = (const float*)d_in[2];
  const float* Wv = (const float*)d_in[3];
  const float* Wo = (const float*)d_in[4];
  const float* bo = (const float*)d_in[5];
  const float* ck = (const float*)d_in[6];
  const float* cv = (const float*)d_in[7];
  const int* sp = (const int*)d_in[8];
  float* out = (float*)d_out;

  float* ws = (float*)d_ws;
  const size_t U = 262144;  // 128*2048 floats
  float* yq = ws;
  float* yk = ws + U * 1;
  float* yv = ws + U * 2;
  float* attn = ws + U * 3;
  float* qkvParts = ws + U * 4;       // [4,28) — dead after sum_qkv_rope_k
  float* po = ws + U * 4;             // reuses qkvParts: 11U -> [4,15)
  float* pm = ws + U * 15;            // 22528 floats
  float* pl = ws + U * 15 + 32768;    // 22528 floats
  float* woParts = ws + U * 16;       // 8U -> [16,24) — after po dead

  // 1) QKV projection, split-K=8
  gemm_f32<<<dim3(32, 8, 3), 256, 0, stream>>>(x, Wq, Wk, Wv, qkvParts);

  // 2) sum parts + RoPE on q,k
  sum_qkv_rope_k<<<dim3(256), 256, 0, stream>>>(qkvParts, yq, yk, yv);

  // 3) flash-decoding attention partials (512 thr, 2q/wave, bf16-LDS dbuf)
  attn_partial_k<<<dim3(KSPLIT, NH, BATCH), 512, 0, stream>>>(
      yq, yk, yv, ck, cv, sp, po, pm, pl);

  // 4) combine -> attn (row-major)
  combine_k<<<dim3(BATCH * NH), 256, 0, stream>>>(po, pm, pl, attn);

  // 5) output projection, split-K=8
  gemm_f32<<<dim3(32, 8, 1), 256, 0, stream>>>(attn, Wo, Wo, Wo, woParts);

  // 6) sum parts + bias -> out
  sum8_bias_k<<<dim3(256), 256, 0, stream>>>(woParts, bo, out);

  (void)in_sizes; (void)n_in; (void)out_size; (void)ws_size;
}

// Round 10
// 252.283 us; speedup vs baseline: 1.6830x; 1.1107x over previous
//
#include <hip/hip_runtime.h>
#include <math.h>

#define EMB 2048
#define NH 16
#define HD 128
#define BATCH 8
#define SEQ 16
#define KVLEN 4096
#define KSPLIT 4
#define MROWS (BATCH * SEQ) /* 128 */

__device__ __forceinline__ float blo(unsigned int w) {
  return __uint_as_float(w << 16);
}
__device__ __forceinline__ float bhi(unsigned int w) {
  return __uint_as_float(w & 0xffff0000u);
}
// pack two floats to bf16x2 (RNE)
__device__ __forceinline__ unsigned int pk2(float x, float y) {
  unsigned int ux = __float_as_uint(x);
  unsigned int uy = __float_as_uint(y);
  ux = (ux + 0x7fffu + ((ux >> 16) & 1u)) >> 16;
  uy = (uy + 0x7fffu + ((uy >> 16) & 1u)) & 0xffff0000u;
  return ux | uy;
}

// ---------------------------------------------------------------------------
// fp32 GEMM: Ypart[r][d] = sum_{c in k-slice} X[r][c] * W[d][c].
// (unchanged from R3/R4 — working)
// ---------------------------------------------------------------------------
__global__ __launch_bounds__(256) void gemm_f32(
    const float* __restrict__ X, const float* __restrict__ W0,
    const float* __restrict__ W1, const float* __restrict__ W2,
    float* __restrict__ Yp) {
  const int z = blockIdx.z;
  const float* __restrict__ W = (z == 0) ? W0 : (z == 1) ? W1 : W2;
  const int kp = blockIdx.y;       // 0..7
  const int c0 = blockIdx.x * 64;  // col block
  const int k0 = kp * 256;         // k-slice start
  const int tid = threadIdx.x;
  const int lane = tid & 63;
  const int wid = tid >> 6;

  const int colg = lane & 15;
  const int rbase = wid * 32 + (lane >> 4) * 8;
  const int perm = lane & 7;

  __shared__ float wt[2][64 * 32];

  float acc[8][4];
#pragma unroll
  for (int i = 0; i < 8; ++i)
#pragma unroll
    for (int c = 0; c < 4; ++c) acc[i][c] = 0.f;

  const int sc0 = tid >> 3, sk = tid & 7;
  const int sc1 = 32 + sc0;
  const float* wsrc0 = &W[(size_t)(c0 + sc0) * EMB + k0 + sk * 4];
  const float* wsrc1 = &W[(size_t)(c0 + sc1) * EMB + k0 + sk * 4];
  const int wo0 = sc0 * 32 + 4 * (sk ^ ((sc0 >> 2) & 7));
  const int wo1 = sc1 * 32 + 4 * (sk ^ ((sc1 >> 2) & 7));

  const float* xbase = X + (size_t)rbase * EMB + k0;

  float4 s0 = *(const float4*)(wsrc0);
  float4 s1 = *(const float4*)(wsrc1);
  *(float4*)&wt[0][wo0] = s0;
  *(float4*)&wt[0][wo1] = s1;
  float4 n0 = *(const float4*)(wsrc0 + 32);
  float4 n1 = *(const float4*)(wsrc1 + 32);
  __syncthreads();

  for (int t = 0; t < 8; ++t) {
    const int buf = t & 1;
    const float* wb = &wt[buf][0];
    const int xoff = t * 32;
#pragma unroll
    for (int k4 = 0; k4 < 8; ++k4) {
      float4 xv[8];
#pragma unroll
      for (int i = 0; i < 8; ++i)
        xv[i] = *(const float4*)&xbase[(size_t)i * EMB + xoff + k4 * 4];
      float4 wv[4];
#pragma unroll
      for (int c = 0; c < 4; ++c)
        wv[c] = *(const float4*)&wb[(4 * colg + c) * 32 + 4 * (k4 ^ perm)];
#pragma unroll
      for (int i = 0; i < 8; ++i)
#pragma unroll
        for (int c = 0; c < 4; ++c)
          acc[i][c] = fmaf(xv[i].w, wv[c].w,
                      fmaf(xv[i].z, wv[c].z,
                      fmaf(xv[i].y, wv[c].y,
                      fmaf(xv[i].x, wv[c].x, acc[i][c]))));
    }
    if (t < 7) {
      *(float4*)&wt[buf ^ 1][wo0] = n0;
      *(float4*)&wt[buf ^ 1][wo1] = n1;
      if (t < 6) {
        n0 = *(const float4*)(wsrc0 + (t + 2) * 32);
        n1 = *(const float4*)(wsrc1 + (t + 2) * 32);
      }
    }
    __syncthreads();
  }

  float* yout = Yp + ((size_t)(z * 8 + kp) * MROWS + rbase) * EMB + c0 + colg * 4;
#pragma unroll
  for (int i = 0; i < 8; ++i)
    *(float4*)&yout[(size_t)i * EMB] =
        make_float4(acc[i][0], acc[i][1], acc[i][2], acc[i][3]);
}

// ---------------------------------------------------------------------------
// Sum 8 split-K parts per matrix; apply RoPE to q,k (z=0,1); v plain.
// ---------------------------------------------------------------------------
__global__ __launch_bounds__(256) void sum_qkv_rope_k(
    const float* __restrict__ parts, float* __restrict__ yq,
    float* __restrict__ yk, float* __restrict__ yv) {
  const int idx4 = blockIdx.x * 256 + threadIdx.x;
  const int idx = idx4 << 2;
  const int row = idx >> 11;
  const int col = idx & 2047;
  const float s = (float)(row & 15);
  const int hd = col & 127;
  const float a0 = s * powf(10000.0f, -(float)hd * (1.0f / 128.0f));
  const float a1 = s * powf(10000.0f, -(float)(hd + 2) * (1.0f / 128.0f));
  float sn0, cs0, sn1, cs1;
  sincosf(a0, &sn0, &cs0);
  sincosf(a1, &sn1, &cs1);
  const float4* p = (const float4*)parts;
  float* outs[3] = {yq, yk, yv};
#pragma unroll
  for (int z = 0; z < 3; ++z) {
    float4 v = make_float4(0.f, 0.f, 0.f, 0.f);
#pragma unroll
    for (int k = 0; k < 8; ++k) {
      float4 a = p[((size_t)(z * 8 + k)) * 65536 + idx4];
      v.x += a.x; v.y += a.y; v.z += a.z; v.w += a.w;
    }
    if (z < 2) {
      float4 r;
      r.x = v.x * cs0 - v.y * sn0;
      r.y = v.x * sn0 + v.y * cs0;
      r.z = v.z * cs1 - v.w * sn1;
      r.w = v.z * sn1 + v.w * cs1;
      v = r;
    }
    ((float4*)outs[z])[idx4] = v;
  }
}

// ---------------------------------------------------------------------------
// sum 8 split-K parts + bias -> final output
// ---------------------------------------------------------------------------
__global__ __launch_bounds__(256) void sum8_bias_k(const float* __restrict__ parts,
                                                   const float* __restrict__ bo,
                                                   float* __restrict__ out) {
  const size_t idx = (size_t)blockIdx.x * 256 + threadIdx.x;
  float4 s = *(const float4*)&bo[(idx << 2) & 2047];
  const float4* p = (const float4*)parts;
#pragma unroll
  for (int k = 0; k < 8; ++k) {
    float4 v = p[(size_t)k * 65536 + idx];
    s.x += v.x; s.y += v.y; s.z += v.z; s.w += v.w;
  }
  ((float4*)out)[idx] = s;
}

// ---------------------------------------------------------------------------
// Flash-decoding attention partial — 512 threads, 2 q-rows per wave,
// bf16-packed Q (halves decoded on demand). Grid (KSPLIT=4, NH, BATCH) =
// 512 blocks = exactly 2/CU; 8-9 tiles per block (prologue amortized).
// Lane = (kslot 0..7: keys kslot+8i, g 0..7: d-slice 16g..+15).
// Register peak ~120 < 128 tier -> no spill, 2 blocks/CU co-resident.
// bf16 LDS tiles, rotate swizzle, dbuf, K/V-split staging:
//   issue K(t+1) -> scores(t) -> B1 -> write K -> issue V(t+1) -> PV(t)
//   -> B2 -> write V -> B3.
// ---------------------------------------------------------------------------
__global__ __launch_bounds__(512) void attn_partial_k(
    const float* __restrict__ q, const float* __restrict__ knew,
    const float* __restrict__ vnew, const float* __restrict__ ck,
    const float* __restrict__ cv, const int* __restrict__ sp_ptr,
    float* __restrict__ po, float* __restrict__ pm, float* __restrict__ pl) {
  const int j = blockIdx.x, h = blockIdx.y, b = blockIdx.z;
  const int tid = threadIdx.x;
  const int wid = tid >> 6;   // 0..7, q rows 2wid..2wid+1
  const int lane = tid & 63;
  const int kslot = lane & 7;
  const int g = lane >> 3;
  const int sp = *sp_ptr;
  const int L = sp + SEQ;
  const int nTiles = (L + 63) >> 6;
  const int tA = (nTiles * j) / KSPLIT;
  const int tB = (nTiles * (j + 1)) / KSPLIT;

  __shared__ unsigned int kt[2][64][64];  // 16 KB per buf (bf16x2)
  __shared__ unsigned int vt[2][64][64];

  const float qscale = 0.08838834764831845f;  // 1/sqrt(128)
  // Q packed bf16: [q][half] -> uint4 = 8 bf16 (pre-scaled)
  uint4 Qp[2][2];
  {
    const float* qb = q + (size_t)(b * SEQ + (wid << 1)) * EMB + h * HD + (g << 4);
#pragma unroll
    for (int qq = 0; qq < 2; ++qq)
#pragma unroll
      for (int h2 = 0; h2 < 2; ++h2) {
        float4 a = *(const float4*)&qb[(size_t)qq * EMB + (h2 << 3)];
        float4 c = *(const float4*)&qb[(size_t)qq * EMB + (h2 << 3) + 4];
        Qp[qq][h2] = make_uint4(
            pk2(a.x * qscale, a.y * qscale), pk2(a.z * qscale, a.w * qscale),
            pk2(c.x * qscale, c.y * qscale), pk2(c.z * qscale, c.w * qscale));
      }
  }

  float acc[2][16];
#pragma unroll
  for (int qq = 0; qq < 2; ++qq)
#pragma unroll
    for (int d = 0; d < 16; ++d) acc[qq][d] = 0.f;
  float m[2] = {-1e30f, -1e30f};
  float l[2] = {0.f, 0.f};

  // staging roles: thread covers rows {rr, rr+32}, chunk cc; slot=(cc+rr)&15
  const int rr = tid >> 4;        // 0..31
  const int cc = tid & 15;        // chunk of 8 d-values
  const int ss = (cc + rr) & 15;  // rotate slot ((k*32)&15==0)
  const size_t ckRow = (size_t)b * KVLEN * EMB + h * HD + cc * 8;
  const size_t knRow = (size_t)b * SEQ * EMB + h * HD + cc * 8;

  float4 pfa[2], pfb[2];  // prefetch regs (K-phase then V-phase)

  // ---- prologue: stage tile tA (K then V) into buf 0 ----
  {
    const int t0 = tA << 6;
#pragma unroll
    for (int k = 0; k < 2; ++k) {
      const int gkE = min(t0 + (k << 5) + rr, L - 1);
      const float* ksp = (gkE < sp) ? ck + ckRow + (size_t)gkE * EMB
                                    : knew + knRow + (size_t)(gkE - sp) * EMB;
      pfa[k] = ((const float4*)ksp)[0];
      pfb[k] = ((const float4*)ksp)[1];
    }
#pragma unroll
    for (int k = 0; k < 2; ++k)
      *(uint4*)&kt[0][(k << 5) + rr][ss << 2] =
          make_uint4(pk2(pfa[k].x, pfa[k].y), pk2(pfa[k].z, pfa[k].w),
                     pk2(pfb[k].x, pfb[k].y), pk2(pfb[k].z, pfb[k].w));
#pragma unroll
    for (int k = 0; k < 2; ++k) {
      const int gkE = min(t0 + (k << 5) + rr, L - 1);
      const float* vsp = (gkE < sp) ? cv + ckRow + (size_t)gkE * EMB
                                    : vnew + knRow + (size_t)(gkE - sp) * EMB;
      pfa[k] = ((const float4*)vsp)[0];
      pfb[k] = ((const float4*)vsp)[1];
    }
#pragma unroll
    for (int k = 0; k < 2; ++k)
      *(uint4*)&vt[0][(k << 5) + rr][ss << 2] =
          make_uint4(pk2(pfa[k].x, pfa[k].y), pk2(pfa[k].z, pfa[k].w),
                     pk2(pfb[k].x, pfb[k].y), pk2(pfb[k].z, pfb[k].w));
  }
  __syncthreads();

  for (int t = tA; t < tB; ++t) {
    const int cur = (t - tA) & 1;
    const bool hn = (t + 1 < tB);
    const int t0 = t << 6;
    const int t0n = (t + 1) << 6;

    // ---- issue K(t+1) loads (consumed after B1; hidden under scores) ----
    if (hn) {
#pragma unroll
      for (int k = 0; k < 2; ++k) {
        const int gkE = min(t0n + (k << 5) + rr, L - 1);
        const float* ksp = (gkE < sp) ? ck + ckRow + (size_t)gkE * EMB
                                      : knew + knRow + (size_t)(gkE - sp) * EMB;
        pfa[k] = ((const float4*)ksp)[0];
        pfb[k] = ((const float4*)ksp)[1];
      }
    }

    // ---- scores: half-major; decode Q half once, then 8 keys ----
    float p8[2][8];
#pragma unroll
    for (int h2 = 0; h2 < 2; ++h2) {
      float qd0[8], qd1[8];
      {
        const uint4 Qa = Qp[0][h2];
        qd0[0] = blo(Qa.x); qd0[1] = bhi(Qa.x); qd0[2] = blo(Qa.y);
        qd0[3] = bhi(Qa.y); qd0[4] = blo(Qa.z); qd0[5] = bhi(Qa.z);
        qd0[6] = blo(Qa.w); qd0[7] = bhi(Qa.w);
        const uint4 Qb = Qp[1][h2];
        qd1[0] = blo(Qb.x); qd1[1] = bhi(Qb.x); qd1[2] = blo(Qb.y);
        qd1[3] = bhi(Qb.y); qd1[4] = blo(Qb.z); qd1[5] = bhi(Qb.z);
        qd1[6] = blo(Qb.w); qd1[7] = bhi(Qb.w);
      }
#pragma unroll
      for (int i = 0; i < 8; ++i) {
        const int r = kslot + (i << 3);
        const int sA = ((g << 1) + h2 + r) & 15;
        const uint4 A = *(const uint4*)&kt[cur][r][sA << 2];
        const float k0 = blo(A.x), k1 = bhi(A.x), k2 = blo(A.y), k3 = bhi(A.y);
        const float k4 = blo(A.z), k5 = bhi(A.z), k6 = blo(A.w), k7 = bhi(A.w);
        float s0 = k0 * qd0[0];
        s0 = fmaf(k1, qd0[1], s0);
        s0 = fmaf(k2, qd0[2], s0);
        s0 = fmaf(k3, qd0[3], s0);
        s0 = fmaf(k4, qd0[4], s0);
        s0 = fmaf(k5, qd0[5], s0);
        s0 = fmaf(k6, qd0[6], s0);
        s0 = fmaf(k7, qd0[7], s0);
        float s1 = k0 * qd1[0];
        s1 = fmaf(k1, qd1[1], s1);
        s1 = fmaf(k2, qd1[2], s1);
        s1 = fmaf(k3, qd1[3], s1);
        s1 = fmaf(k4, qd1[4], s1);
        s1 = fmaf(k5, qd1[5], s1);
        s1 = fmaf(k6, qd1[6], s1);
        s1 = fmaf(k7, qd1[7], s1);
        if (h2 == 0) {
          p8[0][i] = s0;
          p8[1][i] = s1;
        } else {
          p8[0][i] += s0;
          p8[1][i] += s1;
        }
      }
    }
    // ---- reduce over g (lane bits 3..5), mask tail ----
#pragma unroll
    for (int qq = 0; qq < 2; ++qq)
#pragma unroll
      for (int i = 0; i < 8; ++i) {
        float v = p8[qq][i];
        v += __shfl_xor(v, 8);
        v += __shfl_xor(v, 16);
        v += __shfl_xor(v, 32);
        if (t0 + kslot + (i << 3) >= L) v = -3.0e38f;
        p8[qq][i] = v;
      }
    // ---- online softmax per q-row (reduce over kslot bits 0..2) ----
#pragma unroll
    for (int qq = 0; qq < 2; ++qq) {
      float tm = p8[qq][0];
#pragma unroll
      for (int i = 1; i < 8; ++i) tm = fmaxf(tm, p8[qq][i]);
      tm = fmaxf(tm, __shfl_xor(tm, 1));
      tm = fmaxf(tm, __shfl_xor(tm, 2));
      tm = fmaxf(tm, __shfl_xor(tm, 4));
      float mn = fmaxf(m[qq], tm);
      float sc = __expf(m[qq] - mn);
      float ls = 0.f;
#pragma unroll
      for (int i = 0; i < 8; ++i) {
        float pe = __expf(p8[qq][i] - mn);
        p8[qq][i] = pe;
        ls += pe;
      }
      ls += __shfl_xor(ls, 1);
      ls += __shfl_xor(ls, 2);
      ls += __shfl_xor(ls, 4);
      l[qq] = l[qq] * sc + ls;
      m[qq] = mn;
#pragma unroll
      for (int d = 0; d < 16; ++d) acc[qq][d] *= sc;
    }

    __syncthreads();  // B1: all K-reads of buf `cur` done
    if (hn) {
#pragma unroll
      for (int k = 0; k < 2; ++k)
        *(uint4*)&kt[cur ^ 1][(k << 5) + rr][ss << 2] =
            make_uint4(pk2(pfa[k].x, pfa[k].y), pk2(pfa[k].z, pfa[k].w),
                       pk2(pfb[k].x, pfb[k].y), pk2(pfb[k].z, pfb[k].w));
      // ---- issue V(t+1) loads (consumed after B2; hidden under PV) ----
#pragma unroll
      for (int k = 0; k < 2; ++k) {
        const int gkE = min(t0n + (k << 5) + rr, L - 1);
        const float* vsp = (gkE < sp) ? cv + ckRow + (size_t)gkE * EMB
                                      : vnew + knRow + (size_t)(gkE - sp) * EMB;
        pfa[k] = ((const float4*)vsp)[0];
        pfb[k] = ((const float4*)vsp)[1];
      }
    }

    // ---- PV: half-major; lane's 8 keys into its 16-d slice ----
#pragma unroll
    for (int h2 = 0; h2 < 2; ++h2) {
#pragma unroll
      for (int i = 0; i < 8; ++i) {
        const int r = kslot + (i << 3);
        const int sA = ((g << 1) + h2 + r) & 15;
        const uint4 A = *(const uint4*)&vt[cur][r][sA << 2];
        const float v0 = blo(A.x), v1 = bhi(A.x), v2 = blo(A.y), v3 = bhi(A.y);
        const float v4 = blo(A.z), v5 = bhi(A.z), v6 = blo(A.w), v7 = bhi(A.w);
        const float p0 = p8[0][i], p1 = p8[1][i];
        const int d0 = h2 << 3;
        acc[0][d0 + 0] = fmaf(p0, v0, acc[0][d0 + 0]);
        acc[0][d0 + 1] = fmaf(p0, v1, acc[0][d0 + 1]);
        acc[0][d0 + 2] = fmaf(p0, v2, acc[0][d0 + 2]);
        acc[0][d0 + 3] = fmaf(p0, v3, acc[0][d0 + 3]);
        acc[0][d0 + 4] = fmaf(p0, v4, acc[0][d0 + 4]);
        acc[0][d0 + 5] = fmaf(p0, v5, acc[0][d0 + 5]);
        acc[0][d0 + 6] = fmaf(p0, v6, acc[0][d0 + 6]);
        acc[0][d0 + 7] = fmaf(p0, v7, acc[0][d0 + 7]);
        acc[1][d0 + 0] = fmaf(p1, v0, acc[1][d0 + 0]);
        acc[1][d0 + 1] = fmaf(p1, v1, acc[1][d0 + 1]);
        acc[1][d0 + 2] = fmaf(p1, v2, acc[1][d0 + 2]);
        acc[1][d0 + 3] = fmaf(p1, v3, acc[1][d0 + 3]);
        acc[1][d0 + 4] = fmaf(p1, v4, acc[1][d0 + 4]);
        acc[1][d0 + 5] = fmaf(p1, v5, acc[1][d0 + 5]);
        acc[1][d0 + 6] = fmaf(p1, v6, acc[1][d0 + 6]);
        acc[1][d0 + 7] = fmaf(p1, v7, acc[1][d0 + 7]);
      }
    }

    __syncthreads();  // B2: all V-reads of buf `cur` done
    if (hn) {
#pragma unroll
      for (int k = 0; k < 2; ++k)
        *(uint4*)&vt[cur ^ 1][(k << 5) + rr][ss << 2] =
            make_uint4(pk2(pfa[k].x, pfa[k].y), pk2(pfa[k].z, pfa[k].w),
                       pk2(pfb[k].x, pfb[k].y), pk2(pfb[k].z, pfb[k].w));
    }
    __syncthreads();  // B3: next tile fully staged
  }

  // ---- reduce acc over kslot lanes; write partials ----
#pragma unroll
  for (int qq = 0; qq < 2; ++qq)
#pragma unroll
    for (int d = 0; d < 16; ++d) {
      float v = acc[qq][d];
      v += __shfl_xor(v, 1);
      v += __shfl_xor(v, 2);
      v += __shfl_xor(v, 4);
      acc[qq][d] = v;
    }
  const size_t pair = (size_t)(b * NH + h);
  const size_t pb = (pair * KSPLIT + j) * SEQ + (wid << 1);
  if (kslot == 0) {
#pragma unroll
    for (int qq = 0; qq < 2; ++qq)
#pragma unroll
      for (int c = 0; c < 4; ++c)
        *(float4*)&po[(pb + qq) * HD + (g << 4) + (c << 2)] =
            make_float4(acc[qq][(c << 2)], acc[qq][(c << 2) + 1],
                        acc[qq][(c << 2) + 2], acc[qq][(c << 2) + 3]);
  }
  if (lane == 0) {
#pragma unroll
    for (int qq = 0; qq < 2; ++qq) {
      pm[pb + qq] = m[qq];
      pl[pb + qq] = l[qq];
    }
  }
}

// ---------------------------------------------------------------------------
// Combine KSPLIT partials -> attention output (B,S,H*D) row-major.
// ---------------------------------------------------------------------------
__global__ __launch_bounds__(256) void combine_k(const float* __restrict__ po,
                                                 const float* __restrict__ pm,
                                                 const float* __restrict__ pl,
                                                 float* __restrict__ attn) {
  const int pair = blockIdx.x;
  const int b = pair >> 4, h = pair & 15;
  const int tid = threadIdx.x;
  const int d = tid & 127, gq = tid >> 7;
#pragma unroll
  for (int qi = 0; qi < 8; ++qi) {
    int qq = gq * 8 + qi;
    float mj[KSPLIT], lj[KSPLIT];
    float Mx = -1e30f;
#pragma unroll
    for (int jj = 0; jj < KSPLIT; ++jj) {
      mj[jj] = pm[((size_t)pair * KSPLIT + jj) * SEQ + qq];
      lj[jj] = pl[((size_t)pair * KSPLIT + jj) * SEQ + qq];
      Mx = fmaxf(Mx, mj[jj]);
    }
    float Ls = 0.f, o = 0.f;
#pragma unroll
    for (int jj = 0; jj < KSPLIT; ++jj) {
      float w = __expf(mj[jj] - Mx);
      Ls += lj[jj] * w;
      o += po[(((size_t)pair * KSPLIT + jj) * SEQ + qq) * HD + d] * w;
    }
    attn[(size_t)(b * SEQ + qq) * EMB + h * HD + d] = o / Ls;
  }
}

// ---------------------------------------------------------------------------
extern "C" void kernel_launch(void* const* d_in, const int* in_sizes, int n_in,
                              void* d_out, int out_size, void* d_ws,
                              size_t ws_size, hipStream_t stream) {
  const float* x = (const float*)d_in[0];
  const float* Wq = (const float*)d_in[1];
  const float* Wk = (const float*)d_in[2];
  const float* Wv = (const float*)d_in[3];
  const float* Wo = (const float*)d_in[4];
  const float* bo = (const float*)d_in[5];
  const float* ck = (const float*)d_in[6];
  const float* cv = (const float*)d_in[7];
  const int* sp = (const int*)d_in[8];
  float* out = (float*)d_out;

  float* ws = (float*)d_ws;
  const size_t U = 262144;  // 128*2048 floats
  float* yq = ws;
  float* yk = ws + U * 1;
  float* yv = ws + U * 2;
  float* attn = ws + U * 3;
  float* qkvParts = ws + U * 4;       // [4,28) — dead after sum_qkv_rope_k
  float* po = ws + U * 4;             // reuses qkvParts: 4U -> [4,8)
  float* pm = ws + U * 15;            // 8192 floats
  float* pl = ws + U * 15 + 16384;    // 8192 floats
  float* woParts = ws + U * 16;       // 8U -> [16,24)

  // 1) QKV projection, split-K=8
  gemm_f32<<<dim3(32, 8, 3), 256, 0, stream>>>(x, Wq, Wk, Wv, qkvParts);

  // 2) sum parts + RoPE on q,k
  sum_qkv_rope_k<<<dim3(256), 256, 0, stream>>>(qkvParts, yq, yk, yv);

  // 3) flash-decoding attention partials (512 thr, 2q/wave, bf16 Q+KV)
  attn_partial_k<<<dim3(KSPLIT, NH, BATCH), 512, 0, stream>>>(
      yq, yk, yv, ck, cv, sp, po, pm, pl);

  // 4) combine -> attn (row-major)
  combine_k<<<dim3(BATCH * NH), 256, 0, stream>>>(po, pm, pl, attn);

  // 5) output projection, split-K=8
  gemm_f32<<<dim3(32, 8, 1), 256, 0, stream>>>(attn, Wo, Wo, Wo, woParts);

  // 6) sum parts + bias -> out
  sum8_bias_k<<<dim3(256), 256, 0, stream>>>(woParts, bo, out);

  (void)in_sizes; (void)n_in; (void)out_size; (void)ws_size;
}

// Round 11
// 208.164 us; speedup vs baseline: 2.0398x; 1.2119x over previous
//
#include <hip/hip_runtime.h>
#include <math.h>

#define EMB 2048
#define NH 16
#define HD 128
#define BATCH 8
#define SEQ 16
#define KVLEN 4096
#define PARTS 16  /* flash chunks = 4 blocks x 4 waves */
#define MROWS (BATCH * SEQ) /* 128 */

typedef __attribute__((ext_vector_type(8))) short bf16x8;
typedef __attribute__((ext_vector_type(4))) float f32x4;

__device__ __forceinline__ unsigned cvtpk(float lo, float hi) {
  unsigned r;
  asm("v_cvt_pk_bf16_f32 %0, %1, %2" : "=v"(r) : "v"(lo), "v"(hi));
  return r;
}
union U8 {
  uint4 u;
  bf16x8 v;
};
__device__ __forceinline__ bf16x8 pack8(float4 a, float4 b) {
  U8 r;
  r.u.x = cvtpk(a.x, a.y);
  r.u.y = cvtpk(a.z, a.w);
  r.u.z = cvtpk(b.x, b.y);
  r.u.w = cvtpk(b.z, b.w);
  return r.v;
}

// ---------------------------------------------------------------------------
// fp32 GEMM: Ypart[r][d] = sum_{c in k-slice} X[r][c] * W[d][c].
// (unchanged from R3 — working)
// ---------------------------------------------------------------------------
__global__ __launch_bounds__(256) void gemm_f32(
    const float* __restrict__ X, const float* __restrict__ W0,
    const float* __restrict__ W1, const float* __restrict__ W2,
    float* __restrict__ Yp) {
  const int z = blockIdx.z;
  const float* __restrict__ W = (z == 0) ? W0 : (z == 1) ? W1 : W2;
  const int kp = blockIdx.y;
  const int c0 = blockIdx.x * 64;
  const int k0 = kp * 256;
  const int tid = threadIdx.x;
  const int lane = tid & 63;
  const int wid = tid >> 6;

  const int colg = lane & 15;
  const int rbase = wid * 32 + (lane >> 4) * 8;
  const int perm = lane & 7;

  __shared__ float wt[2][64 * 32];

  float acc[8][4];
#pragma unroll
  for (int i = 0; i < 8; ++i)
#pragma unroll
    for (int c = 0; c < 4; ++c) acc[i][c] = 0.f;

  const int sc0 = tid >> 3, sk = tid & 7;
  const int sc1 = 32 + sc0;
  const float* wsrc0 = &W[(size_t)(c0 + sc0) * EMB + k0 + sk * 4];
  const float* wsrc1 = &W[(size_t)(c0 + sc1) * EMB + k0 + sk * 4];
  const int wo0 = sc0 * 32 + 4 * (sk ^ ((sc0 >> 2) & 7));
  const int wo1 = sc1 * 32 + 4 * (sk ^ ((sc1 >> 2) & 7));

  const float* xbase = X + (size_t)rbase * EMB + k0;

  float4 s0 = *(const float4*)(wsrc0);
  float4 s1 = *(const float4*)(wsrc1);
  *(float4*)&wt[0][wo0] = s0;
  *(float4*)&wt[0][wo1] = s1;
  float4 n0 = *(const float4*)(wsrc0 + 32);
  float4 n1 = *(const float4*)(wsrc1 + 32);
  __syncthreads();

  for (int t = 0; t < 8; ++t) {
    const int buf = t & 1;
    const float* wb = &wt[buf][0];
    const int xoff = t * 32;
#pragma unroll
    for (int k4 = 0; k4 < 8; ++k4) {
      float4 xv[8];
#pragma unroll
      for (int i = 0; i < 8; ++i)
        xv[i] = *(const float4*)&xbase[(size_t)i * EMB + xoff + k4 * 4];
      float4 wv[4];
#pragma unroll
      for (int c = 0; c < 4; ++c)
        wv[c] = *(const float4*)&wb[(4 * colg + c) * 32 + 4 * (k4 ^ perm)];
#pragma unroll
      for (int i = 0; i < 8; ++i)
#pragma unroll
        for (int c = 0; c < 4; ++c)
          acc[i][c] = fmaf(xv[i].w, wv[c].w,
                      fmaf(xv[i].z, wv[c].z,
                      fmaf(xv[i].y, wv[c].y,
                      fmaf(xv[i].x, wv[c].x, acc[i][c]))));
    }
    if (t < 7) {
      *(float4*)&wt[buf ^ 1][wo0] = n0;
      *(float4*)&wt[buf ^ 1][wo1] = n1;
      if (t < 6) {
        n0 = *(const float4*)(wsrc0 + (t + 2) * 32);
        n1 = *(const float4*)(wsrc1 + (t + 2) * 32);
      }
    }
    __syncthreads();
  }

  float* yout = Yp + ((size_t)(z * 8 + kp) * MROWS + rbase) * EMB + c0 + colg * 4;
#pragma unroll
  for (int i = 0; i < 8; ++i)
    *(float4*)&yout[(size_t)i * EMB] =
        make_float4(acc[i][0], acc[i][1], acc[i][2], acc[i][3]);
}

// ---------------------------------------------------------------------------
// Sum 8 split-K parts per matrix; apply RoPE to q,k (z=0,1); v plain.
// ---------------------------------------------------------------------------
__global__ __launch_bounds__(256) void sum_qkv_rope_k(
    const float* __restrict__ parts, float* __restrict__ yq,
    float* __restrict__ yk, float* __restrict__ yv) {
  const int idx4 = blockIdx.x * 256 + threadIdx.x;
  const int idx = idx4 << 2;
  const int row = idx >> 11;
  const int col = idx & 2047;
  const float s = (float)(row & 15);
  const int hd = col & 127;
  const float a0 = s * powf(10000.0f, -(float)hd * (1.0f / 128.0f));
  const float a1 = s * powf(10000.0f, -(float)(hd + 2) * (1.0f / 128.0f));
  float sn0, cs0, sn1, cs1;
  sincosf(a0, &sn0, &cs0);
  sincosf(a1, &sn1, &cs1);
  const float4* p = (const float4*)parts;
  float* outs[3] = {yq, yk, yv};
#pragma unroll
  for (int z = 0; z < 3; ++z) {
    float4 v = make_float4(0.f, 0.f, 0.f, 0.f);
#pragma unroll
    for (int k = 0; k < 8; ++k) {
      float4 a = p[((size_t)(z * 8 + k)) * 65536 + idx4];
      v.x += a.x; v.y += a.y; v.z += a.z; v.w += a.w;
    }
    if (z < 2) {
      float4 r;
      r.x = v.x * cs0 - v.y * sn0;
      r.y = v.x * sn0 + v.y * cs0;
      r.z = v.z * cs1 - v.w * sn1;
      r.w = v.z * sn1 + v.w * cs1;
      v = r;
    }
    ((float4*)outs[z])[idx4] = v;
  }
}

// ---------------------------------------------------------------------------
// sum 8 split-K parts + bias -> final output
// ---------------------------------------------------------------------------
__global__ __launch_bounds__(256) void sum8_bias_k(const float* __restrict__ parts,
                                                   const float* __restrict__ bo,
                                                   float* __restrict__ out) {
  const size_t idx = (size_t)blockIdx.x * 256 + threadIdx.x;
  float4 s = *(const float4*)&bo[(idx << 2) & 2047];
  const float4* p = (const float4*)parts;
#pragma unroll
  for (int k = 0; k < 8; ++k) {
    float4 v = p[(size_t)k * 65536 + idx];
    s.x += v.x; s.y += v.y; s.z += v.z; s.w += v.w;
  }
  ((float4*)out)[idx] = s;
}

// ---------------------------------------------------------------------------
// MFMA flash-attention partial. Grid (4, NH, BATCH), 256 thr = 4 waves.
// Each WAVE is an independent flash chunk jw = blockIdx.x*4 + wave (16 parts).
// Per 64-key tile:
//   QK^T: 16x mfma_f32_16x16x32_bf16; A=Q frags (regs, pre-scaled bf16),
//         B=K frags loaded straight from global (lane: 8 consecutive d of
//         key lane&15 -> contiguous 32B; 16x64B dense segments per instr).
//   softmax: C-layout (col=key=lane&15, row=q=(lane>>4)*4+reg, per m89);
//         row reduce = shfl_xor {1,2,4,8}; online m/l per lane (4 rows).
//   P: bf16 to per-wave LDS [16][72] (pad 72 kills bank hotspots),
//         re-read as A-frags (b128, conflict-free).
//   PV: 16x mfma; B=V^T frags dword-gathered from global (4x64B segments,
//         L1-resident rows), packed bf16 via v_cvt_pk_bf16_f32.
// No barriers, no K/V staging. Partials (po,pm,pl) per wave-chunk.
// ---------------------------------------------------------------------------
__global__ __launch_bounds__(256) void attn_mfma_k(
    const float* __restrict__ q, const float* __restrict__ knew,
    const float* __restrict__ vnew, const float* __restrict__ ck,
    const float* __restrict__ cv, const int* __restrict__ sp_ptr,
    float* __restrict__ po, float* __restrict__ pm, float* __restrict__ pl) {
  const int jb = blockIdx.x, h = blockIdx.y, b = blockIdx.z;
  const int tid = threadIdx.x;
  const int w = tid >> 6;
  const int lane = tid & 63;
  const int lr = lane & 15;  // col-lane: key (scores) / d (PV output)
  const int lg = lane >> 4;  // group 0..3
  const int jw = jb * 4 + w;
  const int sp = *sp_ptr;
  const int L = sp + SEQ;
  const int nT = (L + 63) >> 6;
  const int tA = (nT * jw) / PARTS;
  const int tB = (nT * (jw + 1)) / PARTS;

  __shared__ unsigned short Pl[4][16 * 72];
  unsigned short* Pw = &Pl[w][0];

  const float qscale = 0.08838834764831845f;  // 1/sqrt(128)

  // Q A-frags: lane holds Q[q=lr][d = kc*32 + lg*8 + j], pre-scaled bf16
  bf16x8 Qf[4];
  {
    const float* qb = q + (size_t)(b * SEQ + lr) * EMB + h * HD + lg * 8;
#pragma unroll
    for (int kc = 0; kc < 4; ++kc) {
      float4 a = *(const float4*)&qb[kc * 32];
      float4 c = *(const float4*)&qb[kc * 32 + 4];
      a.x *= qscale; a.y *= qscale; a.z *= qscale; a.w *= qscale;
      c.x *= qscale; c.y *= qscale; c.z *= qscale; c.w *= qscale;
      Qf[kc] = pack8(a, c);
    }
  }

  f32x4 Oa[8];
#pragma unroll
  for (int nd = 0; nd < 8; ++nd) Oa[nd] = (f32x4){0.f, 0.f, 0.f, 0.f};
  float m[4] = {-1e30f, -1e30f, -1e30f, -1e30f};
  float l[4] = {0.f, 0.f, 0.f, 0.f};

  for (int t = tA; t < tB; ++t) {
    const int t0 = t << 6;

    // ---- scores: 16 MFMA ----
    f32x4 S[4];
#pragma unroll
    for (int nt = 0; nt < 4; ++nt) S[nt] = (f32x4){0.f, 0.f, 0.f, 0.f};
    const float* kb[4];
#pragma unroll
    for (int nt = 0; nt < 4; ++nt) {
      const int key = t0 + nt * 16 + lr;
      const int ke = min(key, L - 1);
      kb[nt] = ((ke < sp) ? ck + (size_t)(b * KVLEN + ke) * EMB
                          : knew + (size_t)(b * SEQ + ke - sp) * EMB) +
               h * HD + lg * 8;
    }
#pragma unroll
    for (int kc = 0; kc < 4; ++kc) {
#pragma unroll
      for (int nt = 0; nt < 4; ++nt) {
        float4 a = *(const float4*)&kb[nt][kc * 32];
        float4 c = *(const float4*)&kb[nt][kc * 32 + 4];
        S[nt] = __builtin_amdgcn_mfma_f32_16x16x32_bf16(Qf[kc], pack8(a, c),
                                                        S[nt], 0, 0, 0);
      }
    }
    // ---- mask tail keys ----
#pragma unroll
    for (int nt = 0; nt < 4; ++nt)
      if (t0 + nt * 16 + lr >= L) S[nt] = (f32x4){-3e38f, -3e38f, -3e38f, -3e38f};

    // ---- online softmax per q-row r (rows lg*4+r) ----
#pragma unroll
    for (int r = 0; r < 4; ++r) {
      float tm = fmaxf(fmaxf(S[0][r], S[1][r]), fmaxf(S[2][r], S[3][r]));
      tm = fmaxf(tm, __shfl_xor(tm, 1));
      tm = fmaxf(tm, __shfl_xor(tm, 2));
      tm = fmaxf(tm, __shfl_xor(tm, 4));
      tm = fmaxf(tm, __shfl_xor(tm, 8));
      const float mn = fmaxf(m[r], tm);
      const float sc = __expf(m[r] - mn);
      float p0 = __expf(S[0][r] - mn);
      float p1 = __expf(S[1][r] - mn);
      float p2 = __expf(S[2][r] - mn);
      float p3 = __expf(S[3][r] - mn);
      float ls = p0 + p1 + p2 + p3;
      ls += __shfl_xor(ls, 1);
      ls += __shfl_xor(ls, 2);
      ls += __shfl_xor(ls, 4);
      ls += __shfl_xor(ls, 8);
      l[r] = l[r] * sc + ls;
      m[r] = mn;
#pragma unroll
      for (int nd = 0; nd < 8; ++nd) Oa[nd][r] *= sc;
      const int qrow = lg * 4 + r;
      Pw[qrow * 72 + 0 * 16 + lr] = (unsigned short)(cvtpk(p0, p0) & 0xffffu);
      Pw[qrow * 72 + 1 * 16 + lr] = (unsigned short)(cvtpk(p1, p1) & 0xffffu);
      Pw[qrow * 72 + 2 * 16 + lr] = (unsigned short)(cvtpk(p2, p2) & 0xffffu);
      Pw[qrow * 72 + 3 * 16 + lr] = (unsigned short)(cvtpk(p3, p3) & 0xffffu);
    }

    // ---- PV: 16 MFMA; A=P from LDS, B=V^T gathered from global ----
#pragma unroll
    for (int kc2 = 0; kc2 < 2; ++kc2) {
      U8 pa;
      pa.u = *(const uint4*)&Pw[lr * 72 + kc2 * 32 + lg * 8];
      const float* vb[8];
#pragma unroll
      for (int jj = 0; jj < 8; ++jj) {
        const int key = t0 + kc2 * 32 + lg * 8 + jj;
        const int ke = min(key, L - 1);
        vb[jj] = ((ke < sp) ? cv + (size_t)(b * KVLEN + ke) * EMB
                            : vnew + (size_t)(b * SEQ + ke - sp) * EMB) +
                 h * HD + lr;
      }
#pragma unroll
      for (int nd = 0; nd < 8; ++nd) {
        const int off = nd * 16;
        U8 vf;
        vf.u.x = cvtpk(vb[0][off], vb[1][off]);
        vf.u.y = cvtpk(vb[2][off], vb[3][off]);
        vf.u.z = cvtpk(vb[4][off], vb[5][off]);
        vf.u.w = cvtpk(vb[6][off], vb[7][off]);
        Oa[nd] = __builtin_amdgcn_mfma_f32_16x16x32_bf16(pa.v, vf.v, Oa[nd],
                                                         0, 0, 0);
      }
    }
  }

  // ---- write partials: O rows q=lg*4+r, cols d=nd*16+lr ----
  const size_t pair = (size_t)(b * NH + h);
  const size_t pb = (pair * PARTS + jw) * SEQ;
#pragma unroll
  for (int nd = 0; nd < 8; ++nd)
#pragma unroll
    for (int r = 0; r < 4; ++r)
      po[(pb + lg * 4 + r) * HD + nd * 16 + lr] = Oa[nd][r];
  if (lr == 0) {
#pragma unroll
    for (int r = 0; r < 4; ++r) {
      pm[pb + lg * 4 + r] = m[r];
      pl[pb + lg * 4 + r] = l[r];
    }
  }
}

// ---------------------------------------------------------------------------
// Combine PARTS partials -> attention output (B,S,H*D) row-major.
// ---------------------------------------------------------------------------
__global__ __launch_bounds__(256) void combine_k(const float* __restrict__ po,
                                                 const float* __restrict__ pm,
                                                 const float* __restrict__ pl,
                                                 float* __restrict__ attn) {
  const int pair = blockIdx.x;
  const int b = pair >> 4, h = pair & 15;
  const int tid = threadIdx.x;
  const int d = tid & 127, gq = tid >> 7;
#pragma unroll
  for (int qi = 0; qi < 8; ++qi) {
    int qq = gq * 8 + qi;
    float Mx = -1e30f;
    float mj[PARTS], lj[PARTS];
#pragma unroll
    for (int jj = 0; jj < PARTS; ++jj) {
      mj[jj] = pm[((size_t)pair * PARTS + jj) * SEQ + qq];
      lj[jj] = pl[((size_t)pair * PARTS + jj) * SEQ + qq];
      Mx = fmaxf(Mx, mj[jj]);
    }
    float Ls = 0.f, o = 0.f;
#pragma unroll
    for (int jj = 0; jj < PARTS; ++jj) {
      float w = __expf(mj[jj] - Mx);
      Ls += lj[jj] * w;
      o += po[(((size_t)pair * PARTS + jj) * SEQ + qq) * HD + d] * w;
    }
    attn[(size_t)(b * SEQ + qq) * EMB + h * HD + d] = o / Ls;
  }
}

// ---------------------------------------------------------------------------
extern "C" void kernel_launch(void* const* d_in, const int* in_sizes, int n_in,
                              void* d_out, int out_size, void* d_ws,
                              size_t ws_size, hipStream_t stream) {
  const float* x = (const float*)d_in[0];
  const float* Wq = (const float*)d_in[1];
  const float* Wk = (const float*)d_in[2];
  const float* Wv = (const float*)d_in[3];
  const float* Wo = (const float*)d_in[4];
  const float* bo = (const float*)d_in[5];
  const float* ck = (const float*)d_in[6];
  const float* cv = (const float*)d_in[7];
  const int* sp = (const int*)d_in[8];
  float* out = (float*)d_out;

  float* ws = (float*)d_ws;
  const size_t U = 262144;  // 128*2048 floats
  float* yq = ws;
  float* yk = ws + U * 1;
  float* yv = ws + U * 2;
  float* attn = ws + U * 3;
  float* qkvParts = ws + U * 4;       // [4,28) — dead after sum_qkv_rope_k
  float* po = ws + U * 4;             // reuses qkvParts: 16U -> [4,20)
  float* pm = ws + U * 20;            // 32768 floats
  float* pl = ws + U * 20 + 32768;    // 32768 floats
  float* woParts = ws + U * 21;       // 8U -> [21,29)

  // 1) QKV projection, split-K=8
  gemm_f32<<<dim3(32, 8, 3), 256, 0, stream>>>(x, Wq, Wk, Wv, qkvParts);

  // 2) sum parts + RoPE on q,k
  sum_qkv_rope_k<<<dim3(256), 256, 0, stream>>>(qkvParts, yq, yk, yv);

  // 3) MFMA flash-attention partials (16 wave-chunks)
  attn_mfma_k<<<dim3(4, NH, BATCH), 256, 0, stream>>>(
      yq, yk, yv, ck, cv, sp, po, pm, pl);

  // 4) combine -> attn (row-major)
  combine_k<<<dim3(BATCH * NH), 256, 0, stream>>>(po, pm, pl, attn);

  // 5) output projection, split-K=8
  gemm_f32<<<dim3(32, 8, 1), 256, 0, stream>>>(attn, Wo, Wo, Wo, woParts);

  // 6) sum parts + bias -> out
  sum8_bias_k<<<dim3(256), 256, 0, stream>>>(woParts, bo, out);

  (void)in_sizes; (void)n_in; (void)out_size; (void)ws_size;
}